// Round 3
// baseline (270.714 us; speedup 1.0000x reference)
//
#include <hip/hip_runtime.h>
#include <cstdint>
#include <cstddef>

// ---------------------------------------------------------------------------
// Attention_84155589198714: qkv = ctx @ W + b; causal softmax(q k^T / sqrt(N)); @ v
// B=4, N=2048, D=1024. All GEMMs in bf16 MFMA (16x16x32), fp32 accumulate.
//
// R2: XOR bank swizzle (conflicts -> 0); gld16 mainloop = 700 TF at 6 blk/CU.
// R8: 128x64 scores/pv tiles (occupancy) -> 241-254 us total.
// R9/R10: 256x256 8-wave counted-vmcnt QKV (4-phase then exact m201 8-phase)
//   BOTH land ~86-91us, MfmaUtil 23%, everything idle -> schedule-independent
//   serializer.  Theory: addrspace inference fails on templated LDS pointers
//   -> flat_load (counts in vmcnt!) -> every vmcnt(6) waits on fragment reads
//   -> uniform stall.  (m232 corroborates: 8-phase ports off-template go null.)
// R11: A/B split of the QKV gemm, serial dispatches, per-dispatch counters:
//   rows 0-4095  k_gemm_qkv_s: PROVEN 128^2 simple mainloop (641 TF here),
//     fused qk+v epilogues, grid 24x32.
//   rows 4096-8191 k_gemm_qkv_p: R1 8-phase + explicit address_space(3) on
//     all LDS fragment reads (guarantees ds_read_b128, clean vmcnt) +
//     template's lgkmcnt(8) on 12-read phases.  Grid 12x16 = 192 blocks,
//     single round -> dur_us is direct block-time evidence.
// ---------------------------------------------------------------------------

typedef __attribute__((ext_vector_type(8))) __bf16 bf16x8;
typedef __attribute__((ext_vector_type(4))) float f32x4;
#define AS3 __attribute__((address_space(3)))

__device__ inline unsigned short f2bf(float f) {
  unsigned u = __float_as_uint(f);
  u = (u + 0x7FFFu + ((u >> 16) & 1u)) >> 16;  // RNE
  return (unsigned short)u;
}

__device__ inline void gld16(const void* g, void* l) {
  __builtin_amdgcn_global_load_lds(
      (const __attribute__((address_space(1))) unsigned int*)g,
      (AS3 unsigned int*)l, 16, 0, 0);
}

// ===================== 256x256 8-phase machinery (probe) ===================
// LDS per K-tile buffer: 256 rows x 64 cols bf16, row r at r*64, 8-elem chunk
// c of row r at slot c^(r&7).  8 waves 2Mx4N; wave tile 128x64; acc[8][4].

__device__ inline void stage_Ahalf(const unsigned short* Agb, int k0,
                                   unsigned short* Abuf, int half,
                                   int wave, int lrow, int lcol) {
#pragma unroll
  for (int i = 0; i < 2; i++) {
    const int c = wave * 2 + i;
    const int rg = ((c >> 3) << 7) + ((c & 7) << 3) + (half << 6);
    gld16(Agb + (size_t)(rg + lrow) * 1024 + k0 + lcol, Abuf + rg * 64);
  }
}

__device__ inline void stage_Bhalf(const unsigned short* Bgb, int k0,
                                   unsigned short* Bbuf, int half,
                                   int wave, int lrow, int lcol) {
#pragma unroll
  for (int i = 0; i < 2; i++) {
    const int c = wave * 2 + i;
    const int rg = ((c >> 2) << 6) + ((c & 3) << 3) + (half << 5);
    gld16(Bgb + (size_t)(rg + lrow) * 1024 + k0 + lcol, Bbuf + rg * 64);
  }
}

__device__ inline void read_Ahalf(const AS3 unsigned short* buf, int wm, int half,
                                  int lane, bf16x8 (&a)[4][2]) {
#pragma unroll
  for (int ks = 0; ks < 2; ks++) {
    const int csw = ((((ks << 2) + (lane >> 4)) ^ (lane & 7)) << 3);
#pragma unroll
    for (int mi = 0; mi < 4; mi++) {
      const int R = wm * 128 + half * 64 + mi * 16 + (lane & 15);
      a[mi][ks] = *(const AS3 bf16x8*)&buf[R * 64 + csw];
    }
  }
}

__device__ inline void read_Bhalf(const AS3 unsigned short* buf, int wn, int half,
                                  int lane, bf16x8 (&b)[2][2]) {
#pragma unroll
  for (int ks = 0; ks < 2; ks++) {
    const int csw = ((((ks << 2) + (lane >> 4)) ^ (lane & 7)) << 3);
#pragma unroll
    for (int nj = 0; nj < 2; nj++) {
      const int R = wn * 64 + half * 32 + nj * 16 + (lane & 15);
      b[nj][ks] = *(const AS3 bf16x8*)&buf[R * 64 + csw];
    }
  }
}

// 16 MFMA: one C-quadrant x K=64.
__device__ inline void mma_quad(const bf16x8 (&a)[4][2], const bf16x8 (&b)[2][2],
                                f32x4 (&acc)[8][4], const int ah, const int bh) {
#pragma unroll
  for (int ks = 0; ks < 2; ks++)
#pragma unroll
    for (int mi = 0; mi < 4; mi++)
#pragma unroll
      for (int nj = 0; nj < 2; nj++)
        acc[ah * 4 + mi][bh * 2 + nj] = __builtin_amdgcn_mfma_f32_16x16x32_bf16(
            b[nj][ks], a[mi][ks], acc[ah * 4 + mi][bh * 2 + nj], 0, 0, 0);
}

#define QKV_MFMA_PHASE(AFRAG, BFRAG, AH, BH)        \
  __builtin_amdgcn_s_barrier();                     \
  asm volatile("s_waitcnt lgkmcnt(0)" ::: "memory"); \
  __builtin_amdgcn_sched_barrier(0);                \
  __builtin_amdgcn_s_setprio(1);                    \
  mma_quad(AFRAG, BFRAG, acc, AH, BH);              \
  __builtin_amdgcn_s_setprio(0);                    \
  __builtin_amdgcn_sched_barrier(0);                \
  __builtin_amdgcn_s_barrier()

// One iteration: compute K-tiles T0 (buf0) and T1 (buf1); stage aHi(T1) at
// p1, T2 halves at p2-p5, T3 halves at p6-p8.  Checkpoints vmcnt(C4/C8)
// before the p4/p8 opening barriers only.  (RAW/WAR ledger in R10 notes.)
template <bool STG, int C4, int C8>
__device__ inline void qkv_iter(const unsigned short* Agb, const unsigned short* Bgb,
                                int k1, int k2, int k3,
                                const AS3 unsigned short* A0, const AS3 unsigned short* A1,
                                const AS3 unsigned short* B0, const AS3 unsigned short* B1,
                                unsigned short* sA, unsigned short* sB,
                                int wave, int lane, int wm, int wn,
                                f32x4 (&acc)[8][4]) {
  const int lrow = lane >> 3, lcol = ((lane & 7) ^ lrow) * 8;
  bf16x8 aLo[4][2], aHi[4][2], bLo[2][2], bHi[2][2];

  // ---- p1: Q00(T0); stage aHi(T1)
  read_Ahalf(A0, wm, 0, lane, aLo);
  read_Bhalf(B0, wn, 0, lane, bLo);
  stage_Ahalf(Agb, k1, sA + 16384, 1, wave, lrow, lcol);
  asm volatile("s_waitcnt lgkmcnt(8)" ::: "memory");  // 12-read phase cap
  QKV_MFMA_PHASE(aLo, bLo, 0, 0);
  // ---- p2: Q01(T0); stage aLo(T2)
  read_Bhalf(B0, wn, 1, lane, bHi);
  if (STG) stage_Ahalf(Agb, k2, sA, 0, wave, lrow, lcol);
  QKV_MFMA_PHASE(aLo, bHi, 0, 1);
  // ---- p3: Q11(T0); stage bLo(T2)
  read_Ahalf(A0, wm, 1, lane, aHi);
  if (STG) stage_Bhalf(Bgb, k2, sB, 0, wave, lrow, lcol);
  QKV_MFMA_PHASE(aHi, bHi, 1, 1);
  // ---- p4: Q10(T0) from regs; stage bHi(T2); checkpoint C4
  if (STG) stage_Bhalf(Bgb, k2, sB, 1, wave, lrow, lcol);
  if constexpr (C4 >= 0)
    asm volatile("s_waitcnt vmcnt(%0)" ::"i"(C4) : "memory");
  QKV_MFMA_PHASE(aHi, bLo, 1, 0);
  // ---- p5: Q00(T1); stage aHi(T2)
  read_Ahalf(A1, wm, 0, lane, aLo);
  read_Bhalf(B1, wn, 0, lane, bLo);
  if (STG) stage_Ahalf(Agb, k2, sA, 1, wave, lrow, lcol);
  asm volatile("s_waitcnt lgkmcnt(8)" ::: "memory");  // 12-read phase cap
  QKV_MFMA_PHASE(aLo, bLo, 0, 0);
  // ---- p6: Q01(T1); stage aLo(T3)
  read_Bhalf(B1, wn, 1, lane, bHi);
  if (STG) stage_Ahalf(Agb, k3, sA + 16384, 0, wave, lrow, lcol);
  QKV_MFMA_PHASE(aLo, bHi, 0, 1);
  // ---- p7: Q11(T1); stage bLo(T3)
  read_Ahalf(A1, wm, 1, lane, aHi);
  if (STG) stage_Bhalf(Bgb, k3, sB + 16384, 0, wave, lrow, lcol);
  QKV_MFMA_PHASE(aHi, bHi, 1, 1);
  // ---- p8: Q10(T1) from regs; stage bHi(T3); checkpoint C8
  if (STG) stage_Bhalf(Bgb, k3, sB + 16384, 1, wave, lrow, lcol);
  if constexpr (C8 >= 0)
    asm volatile("s_waitcnt vmcnt(%0)" ::"i"(C8) : "memory");
  QKV_MFMA_PHASE(aHi, bLo, 1, 0);
}

// 8-phase probe: rows 4096-8191 (batches 2,3).  Grid 12x16 = 192 blocks.
__global__ __launch_bounds__(512, 2) void k_gemm_qkv_p(
    const unsigned short* __restrict__ A, const unsigned short* __restrict__ Wt,
    const float* __restrict__ bias, unsigned short* __restrict__ qk,
    unsigned short* __restrict__ vT) {
  __shared__ unsigned short sA[2 * 16384];
  __shared__ unsigned short sB[2 * 16384];
  // XCD swizzle: 192 blocks, 192 % 8 == 0 -> bijective (chunk 24).
  const int bid = blockIdx.y * 12 + blockIdx.x;
  const int swz = (bid & 7) * 24 + (bid >> 3);
  const int nb = swz % 12, mb = swz / 12;
  const int tN0 = nb * 256, tM0 = 4096 + mb * 256;
  const unsigned short* Agb = A + (size_t)tM0 * 1024;
  const unsigned short* Bgb = Wt + (size_t)tN0 * 1024;
  const int lane = threadIdx.x & 63, wave = threadIdx.x >> 6;
  const int wm = wave >> 2, wn = wave & 3;
  const int lrow = lane >> 3, lcol = ((lane & 7) ^ lrow) * 8;
  const AS3 unsigned short* A0 = (const AS3 unsigned short*)sA;
  const AS3 unsigned short* A1 = A0 + 16384;
  const AS3 unsigned short* B0 = (const AS3 unsigned short*)sB;
  const AS3 unsigned short* B1 = B0 + 16384;

  f32x4 acc[8][4];
#pragma unroll
  for (int mi = 0; mi < 8; mi++)
#pragma unroll
    for (int nj = 0; nj < 4; nj++) acc[mi][nj] = (f32x4)(0.f);

  // prologue: 7 half-tiles (aLo0,bLo0,bHi0,aHi0,aLo1,bLo1,bHi1); vmcnt(6)
  // -> all of T0 landed.
  stage_Ahalf(Agb, 0, sA, 0, wave, lrow, lcol);
  stage_Bhalf(Bgb, 0, sB, 0, wave, lrow, lcol);
  stage_Bhalf(Bgb, 0, sB, 1, wave, lrow, lcol);
  stage_Ahalf(Agb, 0, sA, 1, wave, lrow, lcol);
  stage_Ahalf(Agb, 64, sA + 16384, 0, wave, lrow, lcol);
  stage_Bhalf(Bgb, 64, sB + 16384, 0, wave, lrow, lcol);
  stage_Bhalf(Bgb, 64, sB + 16384, 1, wave, lrow, lcol);
  asm volatile("s_waitcnt vmcnt(6)" ::: "memory");
  __builtin_amdgcn_s_barrier();

  for (int i = 0; i < 7; i++)
    qkv_iter<true, 6, 6>(Agb, Bgb, (2 * i + 1) * 64, (2 * i + 2) * 64,
                         (2 * i + 3) * 64, A0, A1, B0, B1, sA, sB,
                         wave, lane, wm, wn, acc);
  // final iteration (tiles 14,15): stage only aHi(15) at p1; drain at p4.
  qkv_iter<false, 0, -1>(Agb, Bgb, 15 * 64, 0, 0, A0, A1, B0, B1, sA, sB,
                         wave, lane, wm, wn, acc);

  const int l16 = lane & 15, rq = lane >> 4;
  int m0 = tM0 + wm * 128;
  asm volatile("" : "+v"(m0));  // block LICM of epilogue addresses into loop
  if (tN0 < 2048) {
#pragma unroll
    for (int mi = 0; mi < 8; mi++) {
      const int m = m0 + mi * 16 + l16;
#pragma unroll
      for (int nj = 0; nj < 4; nj++) {
        const int n = tN0 + wn * 64 + nj * 16 + rq * 4;
        const float4 bv = *(const float4*)&bias[n];
        ushort4 o;
        o.x = f2bf(acc[mi][nj][0] + bv.x);
        o.y = f2bf(acc[mi][nj][1] + bv.y);
        o.z = f2bf(acc[mi][nj][2] + bv.z);
        o.w = f2bf(acc[mi][nj][3] + bv.w);
        *(ushort4*)&qk[(size_t)m * 2048 + n] = o;
      }
    }
  } else {
    const int d0b = tN0 - 2048 + wn * 64;
#pragma unroll
    for (int mi = 0; mi < 8; mi++) {
      const int m = m0 + mi * 16 + l16;
      const int b = m >> 11, ns = m & 2047;
#pragma unroll
      for (int nj = 0; nj < 4; nj++) {
        const int d0 = d0b + nj * 16 + rq * 4;
        const float4 bv = *(const float4*)&bias[2048 + d0];
#pragma unroll
        for (int r = 0; r < 4; r++)
          vT[((size_t)(b * 1024 + d0 + r)) * 2048 + ns] =
              f2bf(acc[mi][nj][r] + ((const float*)&bv)[r]);
      }
    }
  }
}

// --------------------- 128x128 tile machinery (proven) ---------------------
__device__ inline void compute_tiles(const unsigned short* As, const unsigned short* Bs,
                                     int lane, int ry, int rx, f32x4 acc[4][4]) {
#pragma unroll
  for (int kk = 0; kk < 64; kk += 32) {
    const int cbase = (kk >> 3) + (lane >> 4);
    const int csw = ((cbase ^ (lane & 7)) << 3);
    bf16x8 a[4], b[4];
#pragma unroll
    for (int mi = 0; mi < 4; mi++)
      a[mi] = *(const bf16x8*)&As[(ry + mi * 16 + (lane & 15)) * 64 + csw];
#pragma unroll
    for (int nj = 0; nj < 4; nj++)
      b[nj] = *(const bf16x8*)&Bs[(rx + nj * 16 + (lane & 15)) * 64 + csw];
#pragma unroll
    for (int mi = 0; mi < 4; mi++)
#pragma unroll
      for (int nj = 0; nj < 4; nj++)
        acc[mi][nj] = __builtin_amdgcn_mfma_f32_16x16x32_bf16(b[nj], a[mi], acc[mi][nj], 0, 0, 0);
  }
}

__device__ inline void mma_mainloop(unsigned short* As, unsigned short* Bs,
                                    const unsigned short* Abase, long strideA,
                                    const unsigned short* Bbase, long strideB,
                                    int kIters, f32x4 acc[4][4]) {
  const int lane = threadIdx.x & 63, wave = threadIdx.x >> 6;
  const int ry = (wave >> 1) * 64, rx = (wave & 1) * 64;
  const int lrow = lane >> 3;
  const int lcol = ((lane & 7) ^ lrow) * 8;
#pragma unroll
  for (int mi = 0; mi < 4; mi++)
#pragma unroll
    for (int nj = 0; nj < 4; nj++) acc[mi][nj] = (f32x4)(0.f);
  for (int kt = 0; kt < kIters; kt++) {
    const int k0 = kt * 64;
    __syncthreads();
#pragma unroll
    for (int c = 0; c < 4; c++) {
      const int q = wave * 4 + c;
      const int row = q * 8 + lrow;
      gld16(Abase + (size_t)row * strideA + k0 + lcol, &As[q * 512]);
      gld16(Bbase + (size_t)row * strideB + k0 + lcol, &Bs[q * 512]);
    }
    __syncthreads();
    compute_tiles(As, Bs, lane, ry, rx, acc);
  }
}

// Proven simple-structure QKV: rows 0-4095 (batches 0,1).  Grid 24x32.
// bx 0-15 -> qk features; bx 16-23 -> v features (vT scatter epilogue).
__global__ __launch_bounds__(256) void k_gemm_qkv_s(
    const unsigned short* __restrict__ A, const unsigned short* __restrict__ Wt,
    const float* __restrict__ bias, unsigned short* __restrict__ qk,
    unsigned short* __restrict__ vT) {
  __shared__ unsigned short As[128 * 64];
  __shared__ unsigned short Bs[128 * 64];
  f32x4 acc[4][4];
  const int bx = blockIdx.x;
  const int tM0 = blockIdx.y * 128;
  const int feat0 = bx * 128;  // 0..3071 feature base
  mma_mainloop(As, Bs, A + (size_t)tM0 * 1024, 1024,
               Wt + (size_t)feat0 * 1024, 1024, 16, acc);
  int tM0v = tM0;
  asm volatile("" : "+v"(tM0v));  // block LICM of epilogue addresses into loop
  const int lane = threadIdx.x & 63, wave = threadIdx.x >> 6;
  const int ry = (wave >> 1) * 64, rx = (wave & 1) * 64;
  const int l16 = lane & 15, rq = lane >> 4;
  if (bx < 16) {
#pragma unroll
    for (int mi = 0; mi < 4; mi++) {
      const int m = tM0v + ry + mi * 16 + l16;
#pragma unroll
      for (int nj = 0; nj < 4; nj++) {
        const int n = feat0 + rx + nj * 16 + rq * 4;
        const float4 bv = *(const float4*)&bias[n];
        ushort4 o;
        o.x = f2bf(acc[mi][nj][0] + bv.x);
        o.y = f2bf(acc[mi][nj][1] + bv.y);
        o.z = f2bf(acc[mi][nj][2] + bv.z);
        o.w = f2bf(acc[mi][nj][3] + bv.w);
        *(ushort4*)&qk[(size_t)m * 2048 + n] = o;
      }
    }
  } else {
    const int tNv = feat0 - 2048;  // v feature block base
#pragma unroll
    for (int mi = 0; mi < 4; mi++) {
      const int m = tM0v + ry + mi * 16 + l16;  // global seq
      const int b = m >> 11, ns = m & 2047;
#pragma unroll
      for (int nj = 0; nj < 4; nj++) {
        const int d0 = tNv + rx + nj * 16 + rq * 4;
        const float4 bv = *(const float4*)&bias[2048 + d0];
#pragma unroll
        for (int r = 0; r < 4; r++)
          vT[((size_t)(b * 1024 + d0 + r)) * 2048 + ns] =
              f2bf(acc[mi][nj][r] + ((const float*)&bv)[r]);
      }
    }
  }
}

// --------------------- 128x64 tile machinery (scores/pv) -------------------
__device__ inline void compute_tiles64(const unsigned short* As, const unsigned short* Bs,
                                       int lane, int ry, int rx, f32x4 acc[4][2]) {
#pragma unroll
  for (int kk = 0; kk < 64; kk += 32) {
    const int cbase = (kk >> 3) + (lane >> 4);
    const int csw = ((cbase ^ (lane & 7)) << 3);
    bf16x8 a[4], b[2];
#pragma unroll
    for (int mi = 0; mi < 4; mi++)
      a[mi] = *(const bf16x8*)&As[(ry + mi * 16 + (lane & 15)) * 64 + csw];
#pragma unroll
    for (int nj = 0; nj < 2; nj++)
      b[nj] = *(const bf16x8*)&Bs[(rx + nj * 16 + (lane & 15)) * 64 + csw];
#pragma unroll
    for (int mi = 0; mi < 4; mi++)
#pragma unroll
      for (int nj = 0; nj < 2; nj++)
        acc[mi][nj] = __builtin_amdgcn_mfma_f32_16x16x32_bf16(b[nj], a[mi], acc[mi][nj], 0, 0, 0);
  }
}

__device__ inline void mma_mainloop64(unsigned short* As, unsigned short* Bs,
                                      const unsigned short* Abase, long strideA,
                                      const unsigned short* Bbase, long strideB,
                                      int kIters, f32x4 acc[4][2]) {
  const int lane = threadIdx.x & 63, wave = threadIdx.x >> 6;
  const int ry = (wave >> 1) * 64, rx = (wave & 1) * 32;
  const int lrow = lane >> 3;
  const int lcol = ((lane & 7) ^ lrow) * 8;
#pragma unroll
  for (int mi = 0; mi < 4; mi++)
#pragma unroll
    for (int nj = 0; nj < 2; nj++) acc[mi][nj] = (f32x4)(0.f);
  for (int kt = 0; kt < kIters; kt++) {
    const int k0 = kt * 64;
    __syncthreads();
#pragma unroll
    for (int c = 0; c < 4; c++) {  // A: 16 chunks of 8 rows -> 4 per wave
      const int q = wave * 4 + c;
      const int row = q * 8 + lrow;
      gld16(Abase + (size_t)row * strideA + k0 + lcol, &As[q * 512]);
    }
#pragma unroll
    for (int c = 0; c < 2; c++) {  // B: 8 chunks -> 2 per wave
      const int q = wave * 2 + c;
      const int row = q * 8 + lrow;
      gld16(Bbase + (size_t)row * strideB + k0 + lcol, &Bs[q * 512]);
    }
    __syncthreads();
    compute_tiles64(As, Bs, lane, ry, rx, acc);
  }
}

// --------------------------- prep kernels ----------------------------------

__global__ void k_convert(const float* __restrict__ x, unsigned short* __restrict__ y, int n4) {
  int i = blockIdx.x * blockDim.x + threadIdx.x;
  if (i >= n4) return;
  float4 v = ((const float4*)x)[i];
  ushort4 o;
  o.x = f2bf(v.x); o.y = f2bf(v.y); o.z = f2bf(v.z); o.w = f2bf(v.w);
  ((ushort4*)y)[i] = o;
}

// W [1024][3072] fp32 -> Wt [3072][1024] bf16
__global__ void k_transpose_w(const float* __restrict__ W, unsigned short* __restrict__ Wt) {
  __shared__ unsigned short sm[64 * 65];
  const int n0 = blockIdx.x * 64;
  const int k0 = blockIdx.y * 64;
  for (int i = threadIdx.x; i < 4096; i += 256) {
    int r = i >> 6, c = i & 63;
    sm[c * 65 + r] = f2bf(W[(size_t)(k0 + r) * 3072 + n0 + c]);
  }
  __syncthreads();
  for (int i = threadIdx.x; i < 4096; i += 256) {
    int r = i >> 6, c = i & 63;
    Wt[(size_t)(n0 + r) * 1024 + k0 + c] = sm[r * 65 + c];
  }
}

// ------------------------- scores / pv kernels -----------------------------

// P_unnorm 128x64 tile + row-sum atomics. Triangular 1-D grid over
// (qb in 16, kb2 in 2qb+2), z = batch. 272 tiles/batch.
__global__ __launch_bounds__(256) void k_scores(const unsigned short* __restrict__ qk,
                                                unsigned short* __restrict__ P,
                                                float* __restrict__ l, float scale) {
  __shared__ unsigned short As[128 * 64];
  __shared__ unsigned short Bs[64 * 64];
  const int t = blockIdx.x, b = blockIdx.z;
  int qb = (int)((sqrtf(4.0f * (float)t + 1.0f) - 1.0f) * 0.5f);  // qb^2+qb <= t
  while (qb * (qb + 1) > t) qb--;
  while ((qb + 1) * (qb + 2) <= t) qb++;
  const int kb2 = t - qb * (qb + 1);  // 64-wide k tile, 0..2qb+1
  f32x4 acc[4][2];
  const unsigned short* Aq = qk + ((size_t)(b * 2048 + qb * 128)) * 2048;
  const unsigned short* Bk = qk + ((size_t)(b * 2048 + kb2 * 64)) * 2048 + 1024;
  mma_mainloop64(As, Bs, Aq, 2048, Bk, 2048, 16, acc);
  const int lane = threadIdx.x & 63, wave = threadIdx.x >> 6;
  const int ry = (wave >> 1) * 64, rx = (wave & 1) * 32;
  const int l16 = lane & 15, rq = lane >> 4;
  unsigned short* Pb = P + ((size_t)(b * 2048 + qb * 128)) * 2048 + (size_t)kb2 * 64;
  float* lb = l + b * 2048 + qb * 128;
#pragma unroll
  for (int mi = 0; mi < 4; mi++) {
    const int m_local = ry + mi * 16 + l16;
    const int qi = qb * 128 + m_local;
    float rowpart = 0.f;
#pragma unroll
    for (int nj = 0; nj < 2; nj++) {
      const int n_base = rx + nj * 16 + rq * 4;
      ushort4 o;
      float p;
#pragma unroll
      for (int r = 0; r < 4; r++) {
        const int kj = kb2 * 64 + n_base + r;
        p = (kj <= qi) ? __expf(acc[mi][nj][r] * scale) : 0.f;
        rowpart += p;
        ((unsigned short*)&o)[r] = f2bf(p);
      }
      *(ushort4*)&Pb[(size_t)m_local * 2048 + n_base] = o;
    }
    rowpart += __shfl_xor(rowpart, 16, 64);
    rowpart += __shfl_xor(rowpart, 32, 64);
    if (rq == 0) atomicAdd(&lb[m_local], rowpart);
  }
}

// out[m][d] = (P[m][:] @ vT[d][:]) / l[m].  128x64 tiles: grid (db2 16, qb 16,
// b 4); causal k-range (qb+1)*2 chunks; qb flipped on half the batches.
__global__ __launch_bounds__(256) void k_pv(const unsigned short* __restrict__ P,
                                            const unsigned short* __restrict__ vT,
                                            const float* __restrict__ l,
                                            float* __restrict__ out) {
  __shared__ unsigned short As[128 * 64];
  __shared__ unsigned short Bs[64 * 64];
  const int db2 = blockIdx.x, b = blockIdx.z;
  int qb = blockIdx.y;
  if (b & 2) qb = 15 - qb;  // balance causal depth across CUs
  f32x4 acc[4][2];
  const unsigned short* Ap = P + ((size_t)(b * 2048 + qb * 128)) * 2048;
  const unsigned short* Bv = vT + ((size_t)(b * 1024 + db2 * 64)) * 2048;
  mma_mainloop64(As, Bs, Ap, 2048, Bv, 2048, (qb + 1) * 2, acc);
  const int lane = threadIdx.x & 63, wave = threadIdx.x >> 6;
  const int ry = (wave >> 1) * 64, rx = (wave & 1) * 32;
  const int l16 = lane & 15, rq = lane >> 4;
  const float* lb = l + b * 2048 + qb * 128;
  float* ob = out + ((size_t)(b * 2048 + qb * 128)) * 1024 + db2 * 64;
#pragma unroll
  for (int mi = 0; mi < 4; mi++) {
    const int m_local = ry + mi * 16 + l16;
    const float inv = 1.0f / lb[m_local];
#pragma unroll
    for (int nj = 0; nj < 2; nj++) {
      const int n_base = rx + nj * 16 + rq * 4;
      float4 o;
      o.x = acc[mi][nj][0] * inv;
      o.y = acc[mi][nj][1] * inv;
      o.z = acc[mi][nj][2] * inv;
      o.w = acc[mi][nj][3] * inv;
      *(float4*)&ob[(size_t)m_local * 1024 + n_base] = o;
    }
  }
}

// ---------------------------------------------------------------------------

extern "C" void kernel_launch(void* const* d_in, const int* in_sizes, int n_in,
                              void* d_out, int out_size, void* d_ws, size_t ws_size,
                              hipStream_t stream) {
  const float* ctx  = (const float*)d_in[0];  // [4,2048,1024]
  const float* W    = (const float*)d_in[1];  // [1024,3072]
  const float* bias = (const float*)d_in[2];  // [3072]
  float* out = (float*)d_out;

  char* ws = (char*)d_ws;
  unsigned short* Actx = (unsigned short*)(ws + 0);          // 16,777,216
  unsigned short* Wt   = (unsigned short*)(ws + 16777216);   //  6,291,456
  unsigned short* qk   = (unsigned short*)(ws + 23068672);   // 33,554,432
  unsigned short* vT   = (unsigned short*)(ws + 56623104);   // 16,777,216
  unsigned short* P    = (unsigned short*)(ws + 73400320);   // 33,554,432
  float*          lsum = (float*)(ws + 106954752);           //     32,768

  hipMemsetAsync(lsum, 0, 4 * 2048 * sizeof(float), stream);
  k_convert<<<8192, 256, 0, stream>>>(ctx, Actx, (8192 * 1024) / 4);
  k_transpose_w<<<dim3(48, 16), 256, 0, stream>>>(W, Wt);
  k_gemm_qkv_s<<<dim3(24, 32), 256, 0, stream>>>(Actx, Wt, bias, qk, vT);
  k_gemm_qkv_p<<<dim3(12, 16), 512, 0, stream>>>(Actx, Wt, bias, qk, vT);
  k_scores<<<dim3(272, 1, 4), 256, 0, stream>>>(qk, P, lsum, 0.022097086912079608f);
  k_pv<<<dim3(16, 16, 4), 256, 0, stream>>>(P, vT, lsum, out);
}

// Round 4
// 261.072 us; speedup vs baseline: 1.0369x; 1.0369x over previous
//
#include <hip/hip_runtime.h>
#include <cstdint>
#include <cstddef>

// ---------------------------------------------------------------------------
// Attention_84155589198714: qkv = ctx @ W + b; causal softmax(q k^T / sqrt(N)); @ v
// B=4, N=2048, D=1024. All GEMMs in bf16 MFMA (16x16x32), fp32 accumulate.
//
// R2: XOR bank swizzle (conflicts -> 0); gld16 mainloop = 700 TF at 6 blk/CU.
// R4: fused epilogues -> LICM VGPR blowup (keep one epilogue per kernel).
// R8: 128x64 scores/pv tiles (occupancy) -> 241-254 us total.
// R9-R11: 256x256 8-wave counted-vmcnt QKV: 4-phase, exact m201 8-phase, and
//   8-phase+address_space(3) all land at ~43/43/38us block time (~600-900 TF
//   equiv).  With 384 tiles the 1.5-round tail dilutes to parity with the
//   split simple kernels (80.6us).  ABANDONED with evidence.  R11's _s arm
//   also re-confirmed R4: fused qk+v epilogue -> VGPR 140, occupancy 10%.
// R12: QKV reverted to R0 proven split (qk 53.6us @641TF + v ~27us).  New
//   experiment on scores/pv (by subtraction ~85-105us combined): 128x64 ->
//   256x64 tiles.  Same acc[4][4]/32-MFMA-per-K-step-per-wave ratio as the
//   641TF gemm (waves stack 4xM over N=64), LDS 40KB -> 4 blk/CU preserved
//   (R8's occupancy objection was to 128x128's 2 blk/CU, not this cell).
//   scores: triangular 144 tiles/batch (576 blocks); pv: (16,8,4)=512 blocks,
//   K=(qb+1)*4 steps, qb flipped on half the batches.
// ---------------------------------------------------------------------------

typedef __attribute__((ext_vector_type(8))) __bf16 bf16x8;
typedef __attribute__((ext_vector_type(4))) float f32x4;

__device__ inline unsigned short f2bf(float f) {
  unsigned u = __float_as_uint(f);
  u = (u + 0x7FFFu + ((u >> 16) & 1u)) >> 16;  // RNE
  return (unsigned short)u;
}

__device__ inline void gld16(const void* g, void* l) {
  __builtin_amdgcn_global_load_lds(
      (const __attribute__((address_space(1))) unsigned int*)g,
      (__attribute__((address_space(3))) unsigned int*)l, 16, 0, 0);
}

// --------------------- shared fragment-compute (proven) --------------------
// LDS tile: row r = 64 elems at r*64; 8-elem chunk c of row r at chunk slot
// c ^ (r&7) (XOR bank swizzle).  Swapped-operand MFMA: output lane&15 = m
// (A row), 4 acc regs = 4 consecutive n (B row).
// Reads A rows ry+mi*16+(lane&15), B rows rx+nj*16+(lane&15): works for any
// LDS tile whose row count covers the indices.
__device__ inline void compute_tiles(const unsigned short* As, const unsigned short* Bs,
                                     int lane, int ry, int rx, f32x4 acc[4][4]) {
#pragma unroll
  for (int kk = 0; kk < 64; kk += 32) {
    const int cbase = (kk >> 3) + (lane >> 4);
    const int csw = ((cbase ^ (lane & 7)) << 3);
    bf16x8 a[4], b[4];
#pragma unroll
    for (int mi = 0; mi < 4; mi++)
      a[mi] = *(const bf16x8*)&As[(ry + mi * 16 + (lane & 15)) * 64 + csw];
#pragma unroll
    for (int nj = 0; nj < 4; nj++)
      b[nj] = *(const bf16x8*)&Bs[(rx + nj * 16 + (lane & 15)) * 64 + csw];
#pragma unroll
    for (int mi = 0; mi < 4; mi++)
#pragma unroll
      for (int nj = 0; nj < 4; nj++)
        acc[mi][nj] = __builtin_amdgcn_mfma_f32_16x16x32_bf16(b[nj], a[mi], acc[mi][nj], 0, 0, 0);
  }
}

// --------------------- 128x128 mainloop (gemms, proven) --------------------
__device__ inline void mma_mainloop(unsigned short* As, unsigned short* Bs,
                                    const unsigned short* Abase, long strideA,
                                    const unsigned short* Bbase, long strideB,
                                    int kIters, f32x4 acc[4][4]) {
  const int lane = threadIdx.x & 63, wave = threadIdx.x >> 6;
  const int ry = (wave >> 1) * 64, rx = (wave & 1) * 64;
  const int lrow = lane >> 3;
  const int lcol = ((lane & 7) ^ lrow) * 8;
#pragma unroll
  for (int mi = 0; mi < 4; mi++)
#pragma unroll
    for (int nj = 0; nj < 4; nj++) acc[mi][nj] = (f32x4)(0.f);
  for (int kt = 0; kt < kIters; kt++) {
    const int k0 = kt * 64;
    __syncthreads();
#pragma unroll
    for (int c = 0; c < 4; c++) {
      const int q = wave * 4 + c;
      const int row = q * 8 + lrow;
      gld16(Abase + (size_t)row * strideA + k0 + lcol, &As[q * 512]);
      gld16(Bbase + (size_t)row * strideB + k0 + lcol, &Bs[q * 512]);
    }
    __syncthreads();
    compute_tiles(As, Bs, lane, ry, rx, acc);
  }
}

// --------------------- 256x64 mainloop (scores/pv, R12) --------------------
// A tile 256x64 (32 chunks -> 8/wave), B tile 64x64 (8 chunks -> 2/wave).
// Waves stack 4xM: wave w owns rows w*64..w*64+63, all 64 N-cols.
__device__ inline void mma_mainloop256(unsigned short* As, unsigned short* Bs,
                                       const unsigned short* Abase, long strideA,
                                       const unsigned short* Bbase, long strideB,
                                       int kIters, f32x4 acc[4][4]) {
  const int lane = threadIdx.x & 63, wave = threadIdx.x >> 6;
  const int ry = wave * 64;
  const int lrow = lane >> 3;
  const int lcol = ((lane & 7) ^ lrow) * 8;
#pragma unroll
  for (int mi = 0; mi < 4; mi++)
#pragma unroll
    for (int nj = 0; nj < 4; nj++) acc[mi][nj] = (f32x4)(0.f);
  for (int kt = 0; kt < kIters; kt++) {
    const int k0 = kt * 64;
    __syncthreads();
#pragma unroll
    for (int c = 0; c < 8; c++) {  // A: 32 chunks of 8 rows -> 8 per wave
      const int q = wave * 8 + c;
      const int row = q * 8 + lrow;
      gld16(Abase + (size_t)row * strideA + k0 + lcol, &As[q * 512]);
    }
#pragma unroll
    for (int c = 0; c < 2; c++) {  // B: 8 chunks -> 2 per wave
      const int q = wave * 2 + c;
      const int row = q * 8 + lrow;
      gld16(Bbase + (size_t)row * strideB + k0 + lcol, &Bs[q * 512]);
    }
    __syncthreads();
    compute_tiles(As, Bs, lane, ry, 0, acc);
  }
}

// --------------------------- prep kernels ----------------------------------

__global__ void k_convert(const float* __restrict__ x, unsigned short* __restrict__ y, int n4) {
  int i = blockIdx.x * blockDim.x + threadIdx.x;
  if (i >= n4) return;
  float4 v = ((const float4*)x)[i];
  ushort4 o;
  o.x = f2bf(v.x); o.y = f2bf(v.y); o.z = f2bf(v.z); o.w = f2bf(v.w);
  ((ushort4*)y)[i] = o;
}

// W [1024][3072] fp32 -> Wt [3072][1024] bf16
__global__ void k_transpose_w(const float* __restrict__ W, unsigned short* __restrict__ Wt) {
  __shared__ unsigned short sm[64 * 65];
  const int n0 = blockIdx.x * 64;
  const int k0 = blockIdx.y * 64;
  for (int i = threadIdx.x; i < 4096; i += 256) {
    int r = i >> 6, c = i & 63;
    sm[c * 65 + r] = f2bf(W[(size_t)(k0 + r) * 3072 + n0 + c]);
  }
  __syncthreads();
  for (int i = threadIdx.x; i < 4096; i += 256) {
    int r = i >> 6, c = i & 63;
    Wt[(size_t)(n0 + r) * 1024 + k0 + c] = sm[r * 65 + c];
  }
}

// --------------------------- GEMM kernels (R0 proven) ----------------------

// qk features: qk[m 8192][n 2048] = ctx @ Wt[n][k] + b, contiguous ushort4.
__global__ __launch_bounds__(256) void k_gemm_qk(const unsigned short* __restrict__ A,
                                                 const unsigned short* __restrict__ Wt,
                                                 const float* __restrict__ bias,
                                                 unsigned short* __restrict__ qk) {
  __shared__ unsigned short As[128 * 64];
  __shared__ unsigned short Bs[128 * 64];
  f32x4 acc[4][4];
  const int tN0 = blockIdx.x * 128;
  const int tM0 = blockIdx.y * 128;
  mma_mainloop(As, Bs, A + (size_t)tM0 * 1024, 1024, Wt + (size_t)tN0 * 1024, 1024, 16, acc);
  const int lane = threadIdx.x & 63, wave = threadIdx.x >> 6;
  const int ry = (wave >> 1) * 64, rx = (wave & 1) * 64;
  const int l16 = lane & 15, rq = lane >> 4;
#pragma unroll
  for (int mi = 0; mi < 4; mi++) {
    const int m = tM0 + ry + mi * 16 + l16;
#pragma unroll
    for (int nj = 0; nj < 4; nj++) {
      const int n = tN0 + rx + nj * 16 + rq * 4;
      const float4 bv = *(const float4*)&bias[n];
      ushort4 o;
      o.x = f2bf(acc[mi][nj][0] + bv.x);
      o.y = f2bf(acc[mi][nj][1] + bv.y);
      o.z = f2bf(acc[mi][nj][2] + bv.z);
      o.w = f2bf(acc[mi][nj][3] + bv.w);
      *(ushort4*)&qk[(size_t)m * 2048 + n] = o;
    }
  }
}

// v features -> vT[b][d][n] directly (swapped layout).  Anti-hoist barrier
// keeps the epilogue address math out of the K-loop's register budget.
__global__ __launch_bounds__(256) void k_gemm_v(const unsigned short* __restrict__ A,
                                                const unsigned short* __restrict__ Wt,
                                                const float* __restrict__ bias,
                                                unsigned short* __restrict__ vT) {
  __shared__ unsigned short As[128 * 64];
  __shared__ unsigned short Bs[128 * 64];
  f32x4 acc[4][4];
  const int tN0 = blockIdx.x * 128;  // v feature block
  const int tM0 = blockIdx.y * 128;
  mma_mainloop(As, Bs, A + (size_t)tM0 * 1024, 1024,
               Wt + (size_t)(2048 + tN0) * 1024, 1024, 16, acc);
  int tM0v = tM0;
  asm volatile("" : "+v"(tM0v));  // block LICM of epilogue addresses into loop
  const int lane = threadIdx.x & 63, wave = threadIdx.x >> 6;
  const int ry = (wave >> 1) * 64, rx = (wave & 1) * 64;
  const int l16 = lane & 15, rq = lane >> 4;
#pragma unroll
  for (int mi = 0; mi < 4; mi++) {
    const int m = tM0v + ry + mi * 16 + l16;  // global seq
    const int b = m >> 11, ns = m & 2047;
#pragma unroll
    for (int nj = 0; nj < 4; nj++) {
      const int d0 = tN0 + rx + nj * 16 + rq * 4;
      const float4 bv = *(const float4*)&bias[2048 + d0];
#pragma unroll
      for (int r = 0; r < 4; r++)
        vT[((size_t)(b * 1024 + d0 + r)) * 2048 + ns] =
            f2bf(acc[mi][nj][r] + ((const float*)&bv)[r]);
    }
  }
}

// ------------------------- scores / pv kernels (256x64) --------------------

// P_unnorm 256x64 tile + row-sum atomics.  Triangular 1-D grid over
// (qb in 8, kb in 4qb+4), z = batch.  144 tiles/batch.
__global__ __launch_bounds__(256) void k_scores(const unsigned short* __restrict__ qk,
                                                unsigned short* __restrict__ P,
                                                float* __restrict__ l, float scale) {
  __shared__ unsigned short As[256 * 64];
  __shared__ unsigned short Bs[64 * 64];
  const int t = blockIdx.x, b = blockIdx.z;
  // tiles before qb = 2*qb*(qb+1); qb in 0..7
  int qb = (int)((sqrtf(2.0f * (float)t + 1.0f) - 1.0f) * 0.5f);
  while (2 * qb * (qb + 1) > t) qb--;
  while (2 * (qb + 1) * (qb + 2) <= t) qb++;
  const int kb = t - 2 * qb * (qb + 1);  // 64-wide k tile, 0..4qb+3
  f32x4 acc[4][4];
  const unsigned short* Aq = qk + ((size_t)(b * 2048 + qb * 256)) * 2048;
  const unsigned short* Bk = qk + ((size_t)(b * 2048 + kb * 64)) * 2048 + 1024;
  mma_mainloop256(As, Bs, Aq, 2048, Bk, 2048, 16, acc);
  const int lane = threadIdx.x & 63, wave = threadIdx.x >> 6;
  const int ry = wave * 64;
  const int l16 = lane & 15, rq = lane >> 4;
  unsigned short* Pb = P + ((size_t)(b * 2048 + qb * 256)) * 2048 + (size_t)kb * 64;
  float* lb = l + b * 2048 + qb * 256;
#pragma unroll
  for (int mi = 0; mi < 4; mi++) {
    const int m_local = ry + mi * 16 + l16;
    const int qi = qb * 256 + m_local;
    float rowpart = 0.f;
#pragma unroll
    for (int nj = 0; nj < 4; nj++) {
      const int n_base = nj * 16 + rq * 4;
      ushort4 o;
      float p;
#pragma unroll
      for (int r = 0; r < 4; r++) {
        const int kj = kb * 64 + n_base + r;
        p = (kj <= qi) ? __expf(acc[mi][nj][r] * scale) : 0.f;
        rowpart += p;
        ((unsigned short*)&o)[r] = f2bf(p);
      }
      *(ushort4*)&Pb[(size_t)m_local * 2048 + n_base] = o;
    }
    rowpart += __shfl_xor(rowpart, 16, 64);
    rowpart += __shfl_xor(rowpart, 32, 64);
    if (rq == 0) atomicAdd(&lb[m_local], rowpart);
  }
}

// out[m][d] = (P[m][:] @ vT[d][:]) / l[m].  256x64 tiles: grid (db2 16, qb 8,
// b 4); causal k-range (qb+1)*4 chunks; qb flipped on half the batches.
__global__ __launch_bounds__(256) void k_pv(const unsigned short* __restrict__ P,
                                            const unsigned short* __restrict__ vT,
                                            const float* __restrict__ l,
                                            float* __restrict__ out) {
  __shared__ unsigned short As[256 * 64];
  __shared__ unsigned short Bs[64 * 64];
  const int db2 = blockIdx.x, b = blockIdx.z;
  int qb = blockIdx.y;
  if (b & 2) qb = 7 - qb;  // balance causal depth across CUs
  f32x4 acc[4][4];
  const unsigned short* Ap = P + ((size_t)(b * 2048 + qb * 256)) * 2048;
  const unsigned short* Bv = vT + ((size_t)(b * 1024 + db2 * 64)) * 2048;
  mma_mainloop256(As, Bs, Ap, 2048, Bv, 2048, (qb + 1) * 4, acc);
  const int lane = threadIdx.x & 63, wave = threadIdx.x >> 6;
  const int ry = wave * 64;
  const int l16 = lane & 15, rq = lane >> 4;
  const float* lb = l + b * 2048 + qb * 256;
  float* ob = out + ((size_t)(b * 2048 + qb * 256)) * 1024 + db2 * 64;
#pragma unroll
  for (int mi = 0; mi < 4; mi++) {
    const int m_local = ry + mi * 16 + l16;
    const float inv = 1.0f / lb[m_local];
#pragma unroll
    for (int nj = 0; nj < 4; nj++) {
      const int n_base = nj * 16 + rq * 4;
      float4 o;
      o.x = acc[mi][nj][0] * inv;
      o.y = acc[mi][nj][1] * inv;
      o.z = acc[mi][nj][2] * inv;
      o.w = acc[mi][nj][3] * inv;
      *(float4*)&ob[(size_t)m_local * 1024 + n_base] = o;
    }
  }
}

// ---------------------------------------------------------------------------

extern "C" void kernel_launch(void* const* d_in, const int* in_sizes, int n_in,
                              void* d_out, int out_size, void* d_ws, size_t ws_size,
                              hipStream_t stream) {
  const float* ctx  = (const float*)d_in[0];  // [4,2048,1024]
  const float* W    = (const float*)d_in[1];  // [1024,3072]
  const float* bias = (const float*)d_in[2];  // [3072]
  float* out = (float*)d_out;

  char* ws = (char*)d_ws;
  unsigned short* Actx = (unsigned short*)(ws + 0);          // 16,777,216
  unsigned short* Wt   = (unsigned short*)(ws + 16777216);   //  6,291,456
  unsigned short* qk   = (unsigned short*)(ws + 23068672);   // 33,554,432
  unsigned short* vT   = (unsigned short*)(ws + 56623104);   // 16,777,216
  unsigned short* P    = (unsigned short*)(ws + 73400320);   // 33,554,432
  float*          lsum = (float*)(ws + 106954752);           //     32,768

  hipMemsetAsync(lsum, 0, 4 * 2048 * sizeof(float), stream);
  k_convert<<<8192, 256, 0, stream>>>(ctx, Actx, (8192 * 1024) / 4);
  k_transpose_w<<<dim3(48, 16), 256, 0, stream>>>(W, Wt);
  k_gemm_qk<<<dim3(16, 64), 256, 0, stream>>>(Actx, Wt, bias, qk);
  k_gemm_v<<<dim3(8, 64), 256, 0, stream>>>(Actx, Wt, bias, vT);
  k_scores<<<dim3(144, 1, 4), 256, 0, stream>>>(qk, P, lsum, 0.022097086912079608f);
  k_pv<<<dim3(16, 8, 4), 256, 0, stream>>>(P, vT, lsum, out);
}

// Round 5
// 242.790 us; speedup vs baseline: 1.1150x; 1.0753x over previous
//
#include <hip/hip_runtime.h>
#include <cstdint>
#include <cstddef>

// ---------------------------------------------------------------------------
// Attention_84155589198714: qkv = ctx @ W + b; causal softmax(q k^T / sqrt(N)); @ v
// B=4, N=2048, D=1024. All GEMMs in bf16 MFMA (16x16x32), fp32 accumulate.
//
// R2: XOR bank swizzle (conflicts -> 0); gld16 mainloop = 700 TF at 6 blk/CU.
// R4: fused epilogues -> LICM VGPR blowup (keep one epilogue per kernel).
// R8: 128x64 scores/pv tiles -> 241-254 us total (best known).
// R9-R11: 256x256 counted-vmcnt QKV (3 variants) all ~600-900 TF block-equiv,
//   parity with split simple kernels after tail dilution.  ABANDONED.
// R12: 256x64 scores/pv: density gain cancelled by causal overcompute
//   (+6-12%) and 2.25-round tail -> neutral (261us).  With pre-R8's 128x128
//   data point, MFMA density is REFUTED as the scores/pv bottleneck.
// R13 (this): revert scores/pv to R8 128x64; INSTRUMENT: split qk into two
//   M-half dispatches (~27us each) so scores/pv surface in rocprof top-5
//   next round (they have never been measured; total-minus-QKV ~= 170us is
//   unexplained vs ~57us ideal).  Safe wins: pv longest-first 1-D grid
//   (deep qb=15 blocks dispatched first); convert+transpose merged into one
//   dispatch (disjoint block ranges, separate code paths -> no VGPR fusion
//   trap) keeping dispatch count at 6.
// ---------------------------------------------------------------------------

typedef __attribute__((ext_vector_type(8))) __bf16 bf16x8;
typedef __attribute__((ext_vector_type(4))) float f32x4;

__device__ inline unsigned short f2bf(float f) {
  unsigned u = __float_as_uint(f);
  u = (u + 0x7FFFu + ((u >> 16) & 1u)) >> 16;  // RNE
  return (unsigned short)u;
}

__device__ inline void gld16(const void* g, void* l) {
  __builtin_amdgcn_global_load_lds(
      (const __attribute__((address_space(1))) unsigned int*)g,
      (__attribute__((address_space(3))) unsigned int*)l, 16, 0, 0);
}

// --------------------- 128x128 tile machinery (gemms) ----------------------
// LDS layout per tile: row r = 64 elems at r*64; 8-elem chunk c of row r at
// chunk position c ^ (r&7) (XOR bank swizzle). Swapped-operand MFMA:
// output lane&15 = m (A row), 4 acc regs = 4 consecutive n (B row).
__device__ inline void compute_tiles(const unsigned short* As, const unsigned short* Bs,
                                     int lane, int ry, int rx, f32x4 acc[4][4]) {
#pragma unroll
  for (int kk = 0; kk < 64; kk += 32) {
    const int cbase = (kk >> 3) + (lane >> 4);
    const int csw = ((cbase ^ (lane & 7)) << 3);
    bf16x8 a[4], b[4];
#pragma unroll
    for (int mi = 0; mi < 4; mi++)
      a[mi] = *(const bf16x8*)&As[(ry + mi * 16 + (lane & 15)) * 64 + csw];
#pragma unroll
    for (int nj = 0; nj < 4; nj++)
      b[nj] = *(const bf16x8*)&Bs[(rx + nj * 16 + (lane & 15)) * 64 + csw];
#pragma unroll
    for (int mi = 0; mi < 4; mi++)
#pragma unroll
      for (int nj = 0; nj < 4; nj++)
        acc[mi][nj] = __builtin_amdgcn_mfma_f32_16x16x32_bf16(b[nj], a[mi], acc[mi][nj], 0, 0, 0);
  }
}

__device__ inline void mma_mainloop(unsigned short* As, unsigned short* Bs,
                                    const unsigned short* Abase, long strideA,
                                    const unsigned short* Bbase, long strideB,
                                    int kIters, f32x4 acc[4][4]) {
  const int lane = threadIdx.x & 63, wave = threadIdx.x >> 6;
  const int ry = (wave >> 1) * 64, rx = (wave & 1) * 64;
  const int lrow = lane >> 3;
  const int lcol = ((lane & 7) ^ lrow) * 8;
#pragma unroll
  for (int mi = 0; mi < 4; mi++)
#pragma unroll
    for (int nj = 0; nj < 4; nj++) acc[mi][nj] = (f32x4)(0.f);
  for (int kt = 0; kt < kIters; kt++) {
    const int k0 = kt * 64;
    __syncthreads();
#pragma unroll
    for (int c = 0; c < 4; c++) {
      const int q = wave * 4 + c;
      const int row = q * 8 + lrow;
      gld16(Abase + (size_t)row * strideA + k0 + lcol, &As[q * 512]);
      gld16(Bbase + (size_t)row * strideB + k0 + lcol, &Bs[q * 512]);
    }
    __syncthreads();
    compute_tiles(As, Bs, lane, ry, rx, acc);
  }
}

// --------------------- 128x64 tile machinery (scores/pv) -------------------
// M=128 (A rows), N=64 (B rows). 4 waves in 2x2; wave-tile 64x32.
// acc[4][2]: mi over 4x16 rows, nj over 2x16 cols.
__device__ inline void compute_tiles64(const unsigned short* As, const unsigned short* Bs,
                                       int lane, int ry, int rx, f32x4 acc[4][2]) {
#pragma unroll
  for (int kk = 0; kk < 64; kk += 32) {
    const int cbase = (kk >> 3) + (lane >> 4);
    const int csw = ((cbase ^ (lane & 7)) << 3);
    bf16x8 a[4], b[2];
#pragma unroll
    for (int mi = 0; mi < 4; mi++)
      a[mi] = *(const bf16x8*)&As[(ry + mi * 16 + (lane & 15)) * 64 + csw];
#pragma unroll
    for (int nj = 0; nj < 2; nj++)
      b[nj] = *(const bf16x8*)&Bs[(rx + nj * 16 + (lane & 15)) * 64 + csw];
#pragma unroll
    for (int mi = 0; mi < 4; mi++)
#pragma unroll
      for (int nj = 0; nj < 2; nj++)
        acc[mi][nj] = __builtin_amdgcn_mfma_f32_16x16x32_bf16(b[nj], a[mi], acc[mi][nj], 0, 0, 0);
  }
}

__device__ inline void mma_mainloop64(unsigned short* As, unsigned short* Bs,
                                      const unsigned short* Abase, long strideA,
                                      const unsigned short* Bbase, long strideB,
                                      int kIters, f32x4 acc[4][2]) {
  const int lane = threadIdx.x & 63, wave = threadIdx.x >> 6;
  const int ry = (wave >> 1) * 64, rx = (wave & 1) * 32;
  const int lrow = lane >> 3;
  const int lcol = ((lane & 7) ^ lrow) * 8;
#pragma unroll
  for (int mi = 0; mi < 4; mi++)
#pragma unroll
    for (int nj = 0; nj < 2; nj++) acc[mi][nj] = (f32x4)(0.f);
  for (int kt = 0; kt < kIters; kt++) {
    const int k0 = kt * 64;
    __syncthreads();
#pragma unroll
    for (int c = 0; c < 4; c++) {  // A: 16 chunks of 8 rows -> 4 per wave
      const int q = wave * 4 + c;
      const int row = q * 8 + lrow;
      gld16(Abase + (size_t)row * strideA + k0 + lcol, &As[q * 512]);
    }
#pragma unroll
    for (int c = 0; c < 2; c++) {  // B: 8 chunks -> 2 per wave
      const int q = wave * 2 + c;
      const int row = q * 8 + lrow;
      gld16(Bbase + (size_t)row * strideB + k0 + lcol, &Bs[q * 512]);
    }
    __syncthreads();
    compute_tiles64(As, Bs, lane, ry, rx, acc);
  }
}

// ------------------------ prep kernel (merged) -----------------------------
// bid < 8192: bf16 convert of ctx (8192*256 float4 elems).
// bid >= 8192: W [1024][3072] fp32 -> Wt [3072][1024] bf16 transpose
//   (768 tiles of 64x64).  Separate code paths, no shared mainloop.
__global__ void k_prep(const float* __restrict__ x, unsigned short* __restrict__ y,
                       const float* __restrict__ W, unsigned short* __restrict__ Wt) {
  __shared__ unsigned short sm[64 * 65];
  const int bid = blockIdx.x;
  if (bid < 8192) {
    const int i = bid * 256 + threadIdx.x;
    float4 v = ((const float4*)x)[i];
    ushort4 o;
    o.x = f2bf(v.x); o.y = f2bf(v.y); o.z = f2bf(v.z); o.w = f2bf(v.w);
    ((ushort4*)y)[i] = o;
  } else {
    const int t = bid - 8192;
    const int n0 = (t % 48) * 64;
    const int k0 = (t / 48) * 64;
    for (int i = threadIdx.x; i < 4096; i += 256) {
      int r = i >> 6, c = i & 63;
      sm[c * 65 + r] = f2bf(W[(size_t)(k0 + r) * 3072 + n0 + c]);
    }
    __syncthreads();
    for (int i = threadIdx.x; i < 4096; i += 256) {
      int r = i >> 6, c = i & 63;
      Wt[(size_t)(n0 + r) * 1024 + k0 + c] = sm[r * 65 + c];
    }
  }
}

// --------------------------- GEMM kernels ----------------------------------

// qk features: qk[m 8192][n 2048] = ctx @ Wt[n][k] + b.  mbase splits the
// M-space across two dispatches (instrumentation: frees rocprof top-5).
__global__ __launch_bounds__(256) void k_gemm_qk(const unsigned short* __restrict__ A,
                                                 const unsigned short* __restrict__ Wt,
                                                 const float* __restrict__ bias,
                                                 unsigned short* __restrict__ qk,
                                                 int mbase) {
  __shared__ unsigned short As[128 * 64];
  __shared__ unsigned short Bs[128 * 64];
  f32x4 acc[4][4];
  const int tN0 = blockIdx.x * 128;
  const int tM0 = mbase + blockIdx.y * 128;
  mma_mainloop(As, Bs, A + (size_t)tM0 * 1024, 1024, Wt + (size_t)tN0 * 1024, 1024, 16, acc);
  const int lane = threadIdx.x & 63, wave = threadIdx.x >> 6;
  const int ry = (wave >> 1) * 64, rx = (wave & 1) * 64;
  const int l16 = lane & 15, rq = lane >> 4;
#pragma unroll
  for (int mi = 0; mi < 4; mi++) {
    const int m = tM0 + ry + mi * 16 + l16;
#pragma unroll
    for (int nj = 0; nj < 4; nj++) {
      const int n = tN0 + rx + nj * 16 + rq * 4;
      const float4 bv = *(const float4*)&bias[n];
      ushort4 o;
      o.x = f2bf(acc[mi][nj][0] + bv.x);
      o.y = f2bf(acc[mi][nj][1] + bv.y);
      o.z = f2bf(acc[mi][nj][2] + bv.z);
      o.w = f2bf(acc[mi][nj][3] + bv.w);
      *(ushort4*)&qk[(size_t)m * 2048 + n] = o;
    }
  }
}

// v features -> vT[b][d][n] directly (swapped layout).  Anti-hoist barrier
// keeps the epilogue address math out of the K-loop's register budget.
__global__ __launch_bounds__(256) void k_gemm_v(const unsigned short* __restrict__ A,
                                                const unsigned short* __restrict__ Wt,
                                                const float* __restrict__ bias,
                                                unsigned short* __restrict__ vT) {
  __shared__ unsigned short As[128 * 64];
  __shared__ unsigned short Bs[128 * 64];
  f32x4 acc[4][4];
  const int tN0 = blockIdx.x * 128;  // v feature block
  const int tM0 = blockIdx.y * 128;
  mma_mainloop(As, Bs, A + (size_t)tM0 * 1024, 1024,
               Wt + (size_t)(2048 + tN0) * 1024, 1024, 16, acc);
  int tM0v = tM0;
  asm volatile("" : "+v"(tM0v));  // block LICM of epilogue addresses into loop
  const int lane = threadIdx.x & 63, wave = threadIdx.x >> 6;
  const int ry = (wave >> 1) * 64, rx = (wave & 1) * 64;
  const int l16 = lane & 15, rq = lane >> 4;
#pragma unroll
  for (int mi = 0; mi < 4; mi++) {
    const int m = tM0v + ry + mi * 16 + l16;  // global seq
    const int b = m >> 11, ns = m & 2047;
#pragma unroll
    for (int nj = 0; nj < 4; nj++) {
      const int d0 = tN0 + rx + nj * 16 + rq * 4;
      const float4 bv = *(const float4*)&bias[2048 + d0];
#pragma unroll
      for (int r = 0; r < 4; r++)
        vT[((size_t)(b * 1024 + d0 + r)) * 2048 + ns] =
            f2bf(acc[mi][nj][r] + ((const float*)&bv)[r]);
    }
  }
}

// ------------------------- scores / pv kernels -----------------------------

// P_unnorm 128x64 tile + row-sum atomics. Triangular 1-D grid over
// (qb in 16, kb2 in 2qb+2), z = batch. 272 tiles/batch.
__global__ __launch_bounds__(256) void k_scores(const unsigned short* __restrict__ qk,
                                                unsigned short* __restrict__ P,
                                                float* __restrict__ l, float scale) {
  __shared__ unsigned short As[128 * 64];
  __shared__ unsigned short Bs[64 * 64];
  const int t = blockIdx.x, b = blockIdx.z;
  int qb = (int)((sqrtf(4.0f * (float)t + 1.0f) - 1.0f) * 0.5f);  // qb^2+qb <= t
  while (qb * (qb + 1) > t) qb--;
  while ((qb + 1) * (qb + 2) <= t) qb++;
  const int kb2 = t - qb * (qb + 1);  // 64-wide k tile, 0..2qb+1
  f32x4 acc[4][2];
  const unsigned short* Aq = qk + ((size_t)(b * 2048 + qb * 128)) * 2048;
  const unsigned short* Bk = qk + ((size_t)(b * 2048 + kb2 * 64)) * 2048 + 1024;
  mma_mainloop64(As, Bs, Aq, 2048, Bk, 2048, 16, acc);
  const int lane = threadIdx.x & 63, wave = threadIdx.x >> 6;
  const int ry = (wave >> 1) * 64, rx = (wave & 1) * 32;
  const int l16 = lane & 15, rq = lane >> 4;
  unsigned short* Pb = P + ((size_t)(b * 2048 + qb * 128)) * 2048 + (size_t)kb2 * 64;
  float* lb = l + b * 2048 + qb * 128;
#pragma unroll
  for (int mi = 0; mi < 4; mi++) {
    const int m_local = ry + mi * 16 + l16;
    const int qi = qb * 128 + m_local;
    float rowpart = 0.f;
#pragma unroll
    for (int nj = 0; nj < 2; nj++) {
      const int n_base = rx + nj * 16 + rq * 4;
      ushort4 o;
      float p;
#pragma unroll
      for (int r = 0; r < 4; r++) {
        const int kj = kb2 * 64 + n_base + r;
        p = (kj <= qi) ? __expf(acc[mi][nj][r] * scale) : 0.f;
        rowpart += p;
        ((unsigned short*)&o)[r] = f2bf(p);
      }
      *(ushort4*)&Pb[(size_t)m_local * 2048 + n_base] = o;
    }
    rowpart += __shfl_xor(rowpart, 16, 64);
    rowpart += __shfl_xor(rowpart, 32, 64);
    if (rq == 0) atomicAdd(&lb[m_local], rowpart);
  }
}

// out[m][d] = (P[m][:] @ vT[d][:]) / l[m].  128x64 tiles, 1-D grid 1024,
// LONGEST-FIRST: t -> qb = 15 - (t>>6) (deep 32-step blocks dispatch first),
// db2 = (t&63)>>2, b = t&3.  Causal k-range (qb+1)*2 chunks.
__global__ __launch_bounds__(256) void k_pv(const unsigned short* __restrict__ P,
                                            const unsigned short* __restrict__ vT,
                                            const float* __restrict__ l,
                                            float* __restrict__ out) {
  __shared__ unsigned short As[128 * 64];
  __shared__ unsigned short Bs[64 * 64];
  const int t = blockIdx.x;
  const int qb = 15 - (t >> 6);
  const int r = t & 63;
  const int db2 = r >> 2;
  const int b = r & 3;
  f32x4 acc[4][2];
  const unsigned short* Ap = P + ((size_t)(b * 2048 + qb * 128)) * 2048;
  const unsigned short* Bv = vT + ((size_t)(b * 1024 + db2 * 64)) * 2048;
  mma_mainloop64(As, Bs, Ap, 2048, Bv, 2048, (qb + 1) * 2, acc);
  const int lane = threadIdx.x & 63, wave = threadIdx.x >> 6;
  const int ry = (wave >> 1) * 64, rx = (wave & 1) * 32;
  const int l16 = lane & 15, rq = lane >> 4;
  const float* lb = l + b * 2048 + qb * 128;
  float* ob = out + ((size_t)(b * 2048 + qb * 128)) * 1024 + db2 * 64;
#pragma unroll
  for (int mi = 0; mi < 4; mi++) {
    const int m_local = ry + mi * 16 + l16;
    const float inv = 1.0f / lb[m_local];
#pragma unroll
    for (int nj = 0; nj < 2; nj++) {
      const int n_base = rx + nj * 16 + rq * 4;
      float4 o;
      o.x = acc[mi][nj][0] * inv;
      o.y = acc[mi][nj][1] * inv;
      o.z = acc[mi][nj][2] * inv;
      o.w = acc[mi][nj][3] * inv;
      *(float4*)&ob[(size_t)m_local * 1024 + n_base] = o;
    }
  }
}

// ---------------------------------------------------------------------------

extern "C" void kernel_launch(void* const* d_in, const int* in_sizes, int n_in,
                              void* d_out, int out_size, void* d_ws, size_t ws_size,
                              hipStream_t stream) {
  const float* ctx  = (const float*)d_in[0];  // [4,2048,1024]
  const float* W    = (const float*)d_in[1];  // [1024,3072]
  const float* bias = (const float*)d_in[2];  // [3072]
  float* out = (float*)d_out;

  char* ws = (char*)d_ws;
  unsigned short* Actx = (unsigned short*)(ws + 0);          // 16,777,216
  unsigned short* Wt   = (unsigned short*)(ws + 16777216);   //  6,291,456
  unsigned short* qk   = (unsigned short*)(ws + 23068672);   // 33,554,432
  unsigned short* vT   = (unsigned short*)(ws + 56623104);   // 16,777,216
  unsigned short* P    = (unsigned short*)(ws + 73400320);   // 33,554,432
  float*          lsum = (float*)(ws + 106954752);           //     32,768

  hipMemsetAsync(lsum, 0, 4 * 2048 * sizeof(float), stream);
  k_prep<<<8960, 256, 0, stream>>>(ctx, Actx, W, Wt);
  k_gemm_qk<<<dim3(16, 32), 256, 0, stream>>>(Actx, Wt, bias, qk, 0);
  k_gemm_qk<<<dim3(16, 32), 256, 0, stream>>>(Actx, Wt, bias, qk, 4096);
  k_gemm_v<<<dim3(8, 64), 256, 0, stream>>>(Actx, Wt, bias, vT);
  k_scores<<<dim3(272, 1, 4), 256, 0, stream>>>(qk, P, lsum, 0.022097086912079608f);
  k_pv<<<1024, 256, 0, stream>>>(P, vT, lsum, out);
}

// Round 6
// 238.745 us; speedup vs baseline: 1.1339x; 1.0169x over previous
//
#include <hip/hip_runtime.h>
#include <cstdint>
#include <cstddef>

// ---------------------------------------------------------------------------
// Attention_84155589198714: qkv = ctx @ W + b; causal softmax(q k^T / sqrt(N)); @ v
// B=4, N=2048, D=1024. All GEMMs in bf16 MFMA (16x16x32), fp32 accumulate.
//
// R2: XOR bank swizzle (conflicts -> 0); gld16 mainloop = 700 TF at 6 blk/CU.
// R4: fused epilogues SHARING one mainloop -> LICM VGPR blowup.  (Disjoint
//   branch merge like k_prep is fine.)
// R8: 128x64 scores/pv tiles -> 241-254 us best known.
// R9-R12: 256-wide tiles + counted-vmcnt schedules: all neutral/worse after
//   tail dilution; ABANDONED with evidence.
// R13: instrumentation round: k_scores = 40.8us (~450 TF); kernel sum ~175us
//   of 242.8 total -> ~65us is inter-dispatch overhead/drain (~8-10us per
//   node boundary, 7 nodes).  Harness poison fills (268MB @6.5TB/s) confirm
//   ~82%-of-peak HBM ceiling.
// R14 (this): cut nodes 7 -> 4 along the dependency chain
//   prep(+lsum zero) -> qk (single 1024-block, proven 53.6us) ->
//   vscores (v-GEMM bid<512 || scores bid>=512, disjoint code paths,
//   shared 32KB LDS carve) -> pv (longest-first, unchanged).
//   Convert widened to 4 float4/thread (2048 blocks).
// ---------------------------------------------------------------------------

typedef __attribute__((ext_vector_type(8))) __bf16 bf16x8;
typedef __attribute__((ext_vector_type(4))) float f32x4;

__device__ inline unsigned short f2bf(float f) {
  unsigned u = __float_as_uint(f);
  u = (u + 0x7FFFu + ((u >> 16) & 1u)) >> 16;  // RNE
  return (unsigned short)u;
}

__device__ inline void gld16(const void* g, void* l) {
  __builtin_amdgcn_global_load_lds(
      (const __attribute__((address_space(1))) unsigned int*)g,
      (__attribute__((address_space(3))) unsigned int*)l, 16, 0, 0);
}

// --------------------- 128x128 tile machinery (gemms) ----------------------
// LDS layout per tile: row r = 64 elems at r*64; 8-elem chunk c of row r at
// chunk position c ^ (r&7) (XOR bank swizzle). Swapped-operand MFMA:
// output lane&15 = m (A row), 4 acc regs = 4 consecutive n (B row).
__device__ inline void compute_tiles(const unsigned short* As, const unsigned short* Bs,
                                     int lane, int ry, int rx, f32x4 acc[4][4]) {
#pragma unroll
  for (int kk = 0; kk < 64; kk += 32) {
    const int cbase = (kk >> 3) + (lane >> 4);
    const int csw = ((cbase ^ (lane & 7)) << 3);
    bf16x8 a[4], b[4];
#pragma unroll
    for (int mi = 0; mi < 4; mi++)
      a[mi] = *(const bf16x8*)&As[(ry + mi * 16 + (lane & 15)) * 64 + csw];
#pragma unroll
    for (int nj = 0; nj < 4; nj++)
      b[nj] = *(const bf16x8*)&Bs[(rx + nj * 16 + (lane & 15)) * 64 + csw];
#pragma unroll
    for (int mi = 0; mi < 4; mi++)
#pragma unroll
      for (int nj = 0; nj < 4; nj++)
        acc[mi][nj] = __builtin_amdgcn_mfma_f32_16x16x32_bf16(b[nj], a[mi], acc[mi][nj], 0, 0, 0);
  }
}

__device__ inline void mma_mainloop(unsigned short* As, unsigned short* Bs,
                                    const unsigned short* Abase, long strideA,
                                    const unsigned short* Bbase, long strideB,
                                    int kIters, f32x4 acc[4][4]) {
  const int lane = threadIdx.x & 63, wave = threadIdx.x >> 6;
  const int ry = (wave >> 1) * 64, rx = (wave & 1) * 64;
  const int lrow = lane >> 3;
  const int lcol = ((lane & 7) ^ lrow) * 8;
#pragma unroll
  for (int mi = 0; mi < 4; mi++)
#pragma unroll
    for (int nj = 0; nj < 4; nj++) acc[mi][nj] = (f32x4)(0.f);
  for (int kt = 0; kt < kIters; kt++) {
    const int k0 = kt * 64;
    __syncthreads();
#pragma unroll
    for (int c = 0; c < 4; c++) {
      const int q = wave * 4 + c;
      const int row = q * 8 + lrow;
      gld16(Abase + (size_t)row * strideA + k0 + lcol, &As[q * 512]);
      gld16(Bbase + (size_t)row * strideB + k0 + lcol, &Bs[q * 512]);
    }
    __syncthreads();
    compute_tiles(As, Bs, lane, ry, rx, acc);
  }
}

// --------------------- 128x64 tile machinery (scores/pv) -------------------
// M=128 (A rows), N=64 (B rows). 4 waves in 2x2; wave-tile 64x32.
// acc[4][2]: mi over 4x16 rows, nj over 2x16 cols.
__device__ inline void compute_tiles64(const unsigned short* As, const unsigned short* Bs,
                                       int lane, int ry, int rx, f32x4 acc[4][2]) {
#pragma unroll
  for (int kk = 0; kk < 64; kk += 32) {
    const int cbase = (kk >> 3) + (lane >> 4);
    const int csw = ((cbase ^ (lane & 7)) << 3);
    bf16x8 a[4], b[2];
#pragma unroll
    for (int mi = 0; mi < 4; mi++)
      a[mi] = *(const bf16x8*)&As[(ry + mi * 16 + (lane & 15)) * 64 + csw];
#pragma unroll
    for (int nj = 0; nj < 2; nj++)
      b[nj] = *(const bf16x8*)&Bs[(rx + nj * 16 + (lane & 15)) * 64 + csw];
#pragma unroll
    for (int mi = 0; mi < 4; mi++)
#pragma unroll
      for (int nj = 0; nj < 2; nj++)
        acc[mi][nj] = __builtin_amdgcn_mfma_f32_16x16x32_bf16(b[nj], a[mi], acc[mi][nj], 0, 0, 0);
  }
}

__device__ inline void mma_mainloop64(unsigned short* As, unsigned short* Bs,
                                      const unsigned short* Abase, long strideA,
                                      const unsigned short* Bbase, long strideB,
                                      int kIters, f32x4 acc[4][2]) {
  const int lane = threadIdx.x & 63, wave = threadIdx.x >> 6;
  const int ry = (wave >> 1) * 64, rx = (wave & 1) * 32;
  const int lrow = lane >> 3;
  const int lcol = ((lane & 7) ^ lrow) * 8;
#pragma unroll
  for (int mi = 0; mi < 4; mi++)
#pragma unroll
    for (int nj = 0; nj < 2; nj++) acc[mi][nj] = (f32x4)(0.f);
  for (int kt = 0; kt < kIters; kt++) {
    const int k0 = kt * 64;
    __syncthreads();
#pragma unroll
    for (int c = 0; c < 4; c++) {  // A: 16 chunks of 8 rows -> 4 per wave
      const int q = wave * 4 + c;
      const int row = q * 8 + lrow;
      gld16(Abase + (size_t)row * strideA + k0 + lcol, &As[q * 512]);
    }
#pragma unroll
    for (int c = 0; c < 2; c++) {  // B: 8 chunks -> 2 per wave
      const int q = wave * 2 + c;
      const int row = q * 8 + lrow;
      gld16(Bbase + (size_t)row * strideB + k0 + lcol, &Bs[q * 512]);
    }
    __syncthreads();
    compute_tiles64(As, Bs, lane, ry, rx, acc);
  }
}

// ------------------------ prep kernel (merged) -----------------------------
// bid < 2048: bf16 convert of ctx, 4 float4/thread (2048*1024 float4 total).
// 2048 <= bid < 2816: W [1024][3072] -> Wt [3072][1024] bf16 (768 64x64 tiles).
// bid == 2816: zero lsum (8192 floats).
__global__ void k_prep(const float* __restrict__ x, unsigned short* __restrict__ y,
                       const float* __restrict__ W, unsigned short* __restrict__ Wt,
                       float* __restrict__ lsum) {
  __shared__ unsigned short sm[64 * 65];
  const int bid = blockIdx.x;
  if (bid < 2048) {
#pragma unroll
    for (int k = 0; k < 4; k++) {
      const int i = bid * 1024 + k * 256 + threadIdx.x;
      float4 v = ((const float4*)x)[i];
      ushort4 o;
      o.x = f2bf(v.x); o.y = f2bf(v.y); o.z = f2bf(v.z); o.w = f2bf(v.w);
      ((ushort4*)y)[i] = o;
    }
  } else if (bid < 2816) {
    const int t = bid - 2048;
    const int n0 = (t % 48) * 64;
    const int k0 = (t / 48) * 64;
    for (int i = threadIdx.x; i < 4096; i += 256) {
      int r = i >> 6, c = i & 63;
      sm[c * 65 + r] = f2bf(W[(size_t)(k0 + r) * 3072 + n0 + c]);
    }
    __syncthreads();
    for (int i = threadIdx.x; i < 4096; i += 256) {
      int r = i >> 6, c = i & 63;
      Wt[(size_t)(n0 + r) * 1024 + k0 + c] = sm[r * 65 + c];
    }
  } else {
#pragma unroll
    for (int k = 0; k < 8; k++)
      ((float4*)lsum)[k * 256 + threadIdx.x] = (float4)(0.f);
  }
}

// --------------------------- qk GEMM (R0 proven) ---------------------------
// qk features: qk[m 8192][n 2048] = ctx @ Wt[n][k] + b, contiguous ushort4.
__global__ __launch_bounds__(256) void k_gemm_qk(const unsigned short* __restrict__ A,
                                                 const unsigned short* __restrict__ Wt,
                                                 const float* __restrict__ bias,
                                                 unsigned short* __restrict__ qk) {
  __shared__ unsigned short As[128 * 64];
  __shared__ unsigned short Bs[128 * 64];
  f32x4 acc[4][4];
  const int tN0 = blockIdx.x * 128;
  const int tM0 = blockIdx.y * 128;
  mma_mainloop(As, Bs, A + (size_t)tM0 * 1024, 1024, Wt + (size_t)tN0 * 1024, 1024, 16, acc);
  const int lane = threadIdx.x & 63, wave = threadIdx.x >> 6;
  const int ry = (wave >> 1) * 64, rx = (wave & 1) * 64;
  const int l16 = lane & 15, rq = lane >> 4;
#pragma unroll
  for (int mi = 0; mi < 4; mi++) {
    const int m = tM0 + ry + mi * 16 + l16;
#pragma unroll
    for (int nj = 0; nj < 4; nj++) {
      const int n = tN0 + rx + nj * 16 + rq * 4;
      const float4 bv = *(const float4*)&bias[n];
      ushort4 o;
      o.x = f2bf(acc[mi][nj][0] + bv.x);
      o.y = f2bf(acc[mi][nj][1] + bv.y);
      o.z = f2bf(acc[mi][nj][2] + bv.z);
      o.w = f2bf(acc[mi][nj][3] + bv.w);
      *(ushort4*)&qk[(size_t)m * 2048 + n] = o;
    }
  }
}

// -------------------- merged v-GEMM + scores dispatch ----------------------
// bid < 512: v features -> vT[b][d][n] (swapped layout), 8x64 tile grid.
// bid >= 512: P_unnorm 128x64 scores tile + row-sum atomics; idx = bid-512,
//   b = idx&3, t = idx>>2 triangular over (qb 16, kb2 2qb+2), 272 tiles/batch.
// Disjoint code paths (k_prep pattern) -- NOT the R4 shared-mainloop trap.
__global__ __launch_bounds__(256) void k_vscores(
    const unsigned short* __restrict__ A, const unsigned short* __restrict__ Wt,
    const float* __restrict__ bias, unsigned short* __restrict__ vT,
    const unsigned short* __restrict__ qk, unsigned short* __restrict__ P,
    float* __restrict__ l, float scale) {
  __shared__ unsigned short smem[16384];  // 32 KB carve
  unsigned short* As = smem;               // 128x64 (16 KB)
  unsigned short* Bs = smem + 8192;        // v: 128x64 (16 KB); scores: 64x64 (8 KB)
  const int bid = blockIdx.x;
  const int lane = threadIdx.x & 63, wave = threadIdx.x >> 6;
  if (bid < 512) {
    // ---------------- v-GEMM branch ----------------
    f32x4 acc[4][4];
    const int tN0 = (bid & 7) * 128;   // v feature block
    const int tM0 = (bid >> 3) * 128;  // seq block
    mma_mainloop(As, Bs, A + (size_t)tM0 * 1024, 1024,
                 Wt + (size_t)(2048 + tN0) * 1024, 1024, 16, acc);
    int tM0v = tM0;
    asm volatile("" : "+v"(tM0v));  // block LICM of epilogue addresses into loop
    const int ry = (wave >> 1) * 64, rx = (wave & 1) * 64;
    const int l16 = lane & 15, rq = lane >> 4;
#pragma unroll
    for (int mi = 0; mi < 4; mi++) {
      const int m = tM0v + ry + mi * 16 + l16;  // global seq
      const int b = m >> 11, ns = m & 2047;
#pragma unroll
      for (int nj = 0; nj < 4; nj++) {
        const int d0 = tN0 + rx + nj * 16 + rq * 4;
        const float4 bv = *(const float4*)&bias[2048 + d0];
#pragma unroll
        for (int r = 0; r < 4; r++)
          vT[((size_t)(b * 1024 + d0 + r)) * 2048 + ns] =
              f2bf(acc[mi][nj][r] + ((const float*)&bv)[r]);
      }
    }
  } else {
    // ---------------- scores branch ----------------
    const int idx = bid - 512;
    const int b = idx & 3;
    const int t = idx >> 2;
    int qb = (int)((sqrtf(4.0f * (float)t + 1.0f) - 1.0f) * 0.5f);  // qb^2+qb <= t
    while (qb * (qb + 1) > t) qb--;
    while ((qb + 1) * (qb + 2) <= t) qb++;
    const int kb2 = t - qb * (qb + 1);  // 64-wide k tile, 0..2qb+1
    f32x4 acc[4][2];
    const unsigned short* Aq = qk + ((size_t)(b * 2048 + qb * 128)) * 2048;
    const unsigned short* Bk = qk + ((size_t)(b * 2048 + kb2 * 64)) * 2048 + 1024;
    mma_mainloop64(As, Bs, Aq, 2048, Bk, 2048, 16, acc);
    const int ry = (wave >> 1) * 64, rx = (wave & 1) * 32;
    const int l16 = lane & 15, rq = lane >> 4;
    unsigned short* Pb = P + ((size_t)(b * 2048 + qb * 128)) * 2048 + (size_t)kb2 * 64;
    float* lb = l + b * 2048 + qb * 128;
#pragma unroll
    for (int mi = 0; mi < 4; mi++) {
      const int m_local = ry + mi * 16 + l16;
      const int qi = qb * 128 + m_local;
      float rowpart = 0.f;
#pragma unroll
      for (int nj = 0; nj < 2; nj++) {
        const int n_base = rx + nj * 16 + rq * 4;
        ushort4 o;
        float p;
#pragma unroll
        for (int r = 0; r < 4; r++) {
          const int kj = kb2 * 64 + n_base + r;
          p = (kj <= qi) ? __expf(acc[mi][nj][r] * scale) : 0.f;
          rowpart += p;
          ((unsigned short*)&o)[r] = f2bf(p);
        }
        *(ushort4*)&Pb[(size_t)m_local * 2048 + n_base] = o;
      }
      rowpart += __shfl_xor(rowpart, 16, 64);
      rowpart += __shfl_xor(rowpart, 32, 64);
      if (rq == 0) atomicAdd(&lb[m_local], rowpart);
    }
  }
}

// ------------------------------- pv kernel ---------------------------------
// out[m][d] = (P[m][:] @ vT[d][:]) / l[m].  128x64 tiles, 1-D grid 1024,
// LONGEST-FIRST: t -> qb = 15 - (t>>6) (deep 32-step blocks dispatch first),
// db2 = (t&63)>>2, b = t&3.  Causal k-range (qb+1)*2 chunks.
__global__ __launch_bounds__(256) void k_pv(const unsigned short* __restrict__ P,
                                            const unsigned short* __restrict__ vT,
                                            const float* __restrict__ l,
                                            float* __restrict__ out) {
  __shared__ unsigned short As[128 * 64];
  __shared__ unsigned short Bs[64 * 64];
  const int t = blockIdx.x;
  const int qb = 15 - (t >> 6);
  const int r = t & 63;
  const int db2 = r >> 2;
  const int b = r & 3;
  f32x4 acc[4][2];
  const unsigned short* Ap = P + ((size_t)(b * 2048 + qb * 128)) * 2048;
  const unsigned short* Bv = vT + ((size_t)(b * 1024 + db2 * 64)) * 2048;
  mma_mainloop64(As, Bs, Ap, 2048, Bv, 2048, (qb + 1) * 2, acc);
  const int lane = threadIdx.x & 63, wave = threadIdx.x >> 6;
  const int ry = (wave >> 1) * 64, rx = (wave & 1) * 32;
  const int l16 = lane & 15, rq = lane >> 4;
  const float* lb = l + b * 2048 + qb * 128;
  float* ob = out + ((size_t)(b * 2048 + qb * 128)) * 1024 + db2 * 64;
#pragma unroll
  for (int mi = 0; mi < 4; mi++) {
    const int m_local = ry + mi * 16 + l16;
    const float inv = 1.0f / lb[m_local];
#pragma unroll
    for (int nj = 0; nj < 2; nj++) {
      const int n_base = rx + nj * 16 + rq * 4;
      float4 o;
      o.x = acc[mi][nj][0] * inv;
      o.y = acc[mi][nj][1] * inv;
      o.z = acc[mi][nj][2] * inv;
      o.w = acc[mi][nj][3] * inv;
      *(float4*)&ob[(size_t)m_local * 1024 + n_base] = o;
    }
  }
}

// ---------------------------------------------------------------------------

extern "C" void kernel_launch(void* const* d_in, const int* in_sizes, int n_in,
                              void* d_out, int out_size, void* d_ws, size_t ws_size,
                              hipStream_t stream) {
  const float* ctx  = (const float*)d_in[0];  // [4,2048,1024]
  const float* W    = (const float*)d_in[1];  // [1024,3072]
  const float* bias = (const float*)d_in[2];  // [3072]
  float* out = (float*)d_out;

  char* ws = (char*)d_ws;
  unsigned short* Actx = (unsigned short*)(ws + 0);          // 16,777,216
  unsigned short* Wt   = (unsigned short*)(ws + 16777216);   //  6,291,456
  unsigned short* qk   = (unsigned short*)(ws + 23068672);   // 33,554,432
  unsigned short* vT   = (unsigned short*)(ws + 56623104);   // 16,777,216
  unsigned short* P    = (unsigned short*)(ws + 73400320);   // 33,554,432
  float*          lsum = (float*)(ws + 106954752);           //     32,768

  k_prep<<<2817, 256, 0, stream>>>(ctx, Actx, W, Wt, lsum);
  k_gemm_qk<<<dim3(16, 64), 256, 0, stream>>>(Actx, Wt, bias, qk);
  k_vscores<<<1600, 256, 0, stream>>>(Actx, Wt, bias, vT, qk, P, lsum,
                                      0.022097086912079608f);
  k_pv<<<1024, 256, 0, stream>>>(P, vT, lsum, out);
}

// Round 7
// 238.285 us; speedup vs baseline: 1.1361x; 1.0019x over previous
//
#include <hip/hip_runtime.h>
#include <cstdint>
#include <cstddef>

// ---------------------------------------------------------------------------
// Attention_84155589198714: qkv = ctx @ W + b; causal softmax(q k^T / sqrt(N)); @ v
// B=4, N=2048, D=1024. All GEMMs in bf16 MFMA (16x16x32), fp32 accumulate.
//
// R2: XOR bank swizzle (conflicts -> 0); gld16 mainloop = 700 TF at 6 blk/CU.
// R4: fused epilogues SHARING one mainloop -> LICM VGPR blowup.  (Disjoint
//   branch merge is fine ONLY within one register class -- see R14.)
// R8: 128x64 scores/pv tiles -> 241-254 us best known.
// R9-R12: 256-wide tiles + counted-vmcnt schedules: neutral/worse. ABANDONED.
// R13: instrumentation: scores=40.8us (~450 TF); kernel sum ~175us of 242.8
//   -> ~65us inter-dispatch residue (~7-11us per boundary).
// R14: merge v+scores -> residue 47us (saved 21) BUT VGPR 56->108 pushed the
//   scores blocks from 24 to 16 waves/CU (m69 bracket): 88.4us vs 68 split.
//   Net -4us.  LESSON: merge only kernels in the SAME VGPR/occupancy class.
// R15 (this): re-pair the merge by register class.  qk (VGPR 80) + v (VGPR
//   80) merged into k_gemm_qkv (disjoint branches, both 32KB LDS, both 4
//   blk/CU -> zero occupancy cost, one less drain).  scores & pv restored to
//   proven standalone forms (56 VGPR, 6 blk/CU).  Still 4 dispatches:
//   prep(+lsum) -> gemm_qkv -> scores -> pv.
// ---------------------------------------------------------------------------

typedef __attribute__((ext_vector_type(8))) __bf16 bf16x8;
typedef __attribute__((ext_vector_type(4))) float f32x4;

__device__ inline unsigned short f2bf(float f) {
  unsigned u = __float_as_uint(f);
  u = (u + 0x7FFFu + ((u >> 16) & 1u)) >> 16;  // RNE
  return (unsigned short)u;
}

__device__ inline void gld16(const void* g, void* l) {
  __builtin_amdgcn_global_load_lds(
      (const __attribute__((address_space(1))) unsigned int*)g,
      (__attribute__((address_space(3))) unsigned int*)l, 16, 0, 0);
}

// --------------------- 128x128 tile machinery (gemms) ----------------------
// LDS layout per tile: row r = 64 elems at r*64; 8-elem chunk c of row r at
// chunk position c ^ (r&7) (XOR bank swizzle). Swapped-operand MFMA:
// output lane&15 = m (A row), 4 acc regs = 4 consecutive n (B row).
__device__ inline void compute_tiles(const unsigned short* As, const unsigned short* Bs,
                                     int lane, int ry, int rx, f32x4 acc[4][4]) {
#pragma unroll
  for (int kk = 0; kk < 64; kk += 32) {
    const int cbase = (kk >> 3) + (lane >> 4);
    const int csw = ((cbase ^ (lane & 7)) << 3);
    bf16x8 a[4], b[4];
#pragma unroll
    for (int mi = 0; mi < 4; mi++)
      a[mi] = *(const bf16x8*)&As[(ry + mi * 16 + (lane & 15)) * 64 + csw];
#pragma unroll
    for (int nj = 0; nj < 4; nj++)
      b[nj] = *(const bf16x8*)&Bs[(rx + nj * 16 + (lane & 15)) * 64 + csw];
#pragma unroll
    for (int mi = 0; mi < 4; mi++)
#pragma unroll
      for (int nj = 0; nj < 4; nj++)
        acc[mi][nj] = __builtin_amdgcn_mfma_f32_16x16x32_bf16(b[nj], a[mi], acc[mi][nj], 0, 0, 0);
  }
}

__device__ inline void mma_mainloop(unsigned short* As, unsigned short* Bs,
                                    const unsigned short* Abase, long strideA,
                                    const unsigned short* Bbase, long strideB,
                                    int kIters, f32x4 acc[4][4]) {
  const int lane = threadIdx.x & 63, wave = threadIdx.x >> 6;
  const int ry = (wave >> 1) * 64, rx = (wave & 1) * 64;
  const int lrow = lane >> 3;
  const int lcol = ((lane & 7) ^ lrow) * 8;
#pragma unroll
  for (int mi = 0; mi < 4; mi++)
#pragma unroll
    for (int nj = 0; nj < 4; nj++) acc[mi][nj] = (f32x4)(0.f);
  for (int kt = 0; kt < kIters; kt++) {
    const int k0 = kt * 64;
    __syncthreads();
#pragma unroll
    for (int c = 0; c < 4; c++) {
      const int q = wave * 4 + c;
      const int row = q * 8 + lrow;
      gld16(Abase + (size_t)row * strideA + k0 + lcol, &As[q * 512]);
      gld16(Bbase + (size_t)row * strideB + k0 + lcol, &Bs[q * 512]);
    }
    __syncthreads();
    compute_tiles(As, Bs, lane, ry, rx, acc);
  }
}

// --------------------- 128x64 tile machinery (scores/pv) -------------------
// M=128 (A rows), N=64 (B rows). 4 waves in 2x2; wave-tile 64x32.
// acc[4][2]: mi over 4x16 rows, nj over 2x16 cols.
__device__ inline void compute_tiles64(const unsigned short* As, const unsigned short* Bs,
                                       int lane, int ry, int rx, f32x4 acc[4][2]) {
#pragma unroll
  for (int kk = 0; kk < 64; kk += 32) {
    const int cbase = (kk >> 3) + (lane >> 4);
    const int csw = ((cbase ^ (lane & 7)) << 3);
    bf16x8 a[4], b[2];
#pragma unroll
    for (int mi = 0; mi < 4; mi++)
      a[mi] = *(const bf16x8*)&As[(ry + mi * 16 + (lane & 15)) * 64 + csw];
#pragma unroll
    for (int nj = 0; nj < 2; nj++)
      b[nj] = *(const bf16x8*)&Bs[(rx + nj * 16 + (lane & 15)) * 64 + csw];
#pragma unroll
    for (int mi = 0; mi < 4; mi++)
#pragma unroll
      for (int nj = 0; nj < 2; nj++)
        acc[mi][nj] = __builtin_amdgcn_mfma_f32_16x16x32_bf16(b[nj], a[mi], acc[mi][nj], 0, 0, 0);
  }
}

__device__ inline void mma_mainloop64(unsigned short* As, unsigned short* Bs,
                                      const unsigned short* Abase, long strideA,
                                      const unsigned short* Bbase, long strideB,
                                      int kIters, f32x4 acc[4][2]) {
  const int lane = threadIdx.x & 63, wave = threadIdx.x >> 6;
  const int ry = (wave >> 1) * 64, rx = (wave & 1) * 32;
  const int lrow = lane >> 3;
  const int lcol = ((lane & 7) ^ lrow) * 8;
#pragma unroll
  for (int mi = 0; mi < 4; mi++)
#pragma unroll
    for (int nj = 0; nj < 2; nj++) acc[mi][nj] = (f32x4)(0.f);
  for (int kt = 0; kt < kIters; kt++) {
    const int k0 = kt * 64;
    __syncthreads();
#pragma unroll
    for (int c = 0; c < 4; c++) {  // A: 16 chunks of 8 rows -> 4 per wave
      const int q = wave * 4 + c;
      const int row = q * 8 + lrow;
      gld16(Abase + (size_t)row * strideA + k0 + lcol, &As[q * 512]);
    }
#pragma unroll
    for (int c = 0; c < 2; c++) {  // B: 8 chunks -> 2 per wave
      const int q = wave * 2 + c;
      const int row = q * 8 + lrow;
      gld16(Bbase + (size_t)row * strideB + k0 + lcol, &Bs[q * 512]);
    }
    __syncthreads();
    compute_tiles64(As, Bs, lane, ry, rx, acc);
  }
}

// ------------------------ prep kernel (merged) -----------------------------
// bid < 2048: bf16 convert of ctx, 4 float4/thread (2048*1024 float4 total).
// 2048 <= bid < 2816: W [1024][3072] -> Wt [3072][1024] bf16 (768 64x64 tiles).
// bid == 2816: zero lsum (8192 floats).
__global__ void k_prep(const float* __restrict__ x, unsigned short* __restrict__ y,
                       const float* __restrict__ W, unsigned short* __restrict__ Wt,
                       float* __restrict__ lsum) {
  __shared__ unsigned short sm[64 * 65];
  const int bid = blockIdx.x;
  if (bid < 2048) {
#pragma unroll
    for (int k = 0; k < 4; k++) {
      const int i = bid * 1024 + k * 256 + threadIdx.x;
      float4 v = ((const float4*)x)[i];
      ushort4 o;
      o.x = f2bf(v.x); o.y = f2bf(v.y); o.z = f2bf(v.z); o.w = f2bf(v.w);
      ((ushort4*)y)[i] = o;
    }
  } else if (bid < 2816) {
    const int t = bid - 2048;
    const int n0 = (t % 48) * 64;
    const int k0 = (t / 48) * 64;
    for (int i = threadIdx.x; i < 4096; i += 256) {
      int r = i >> 6, c = i & 63;
      sm[c * 65 + r] = f2bf(W[(size_t)(k0 + r) * 3072 + n0 + c]);
    }
    __syncthreads();
    for (int i = threadIdx.x; i < 4096; i += 256) {
      int r = i >> 6, c = i & 63;
      Wt[(size_t)(n0 + r) * 1024 + k0 + c] = sm[r * 65 + c];
    }
  } else {
#pragma unroll
    for (int k = 0; k < 8; k++)
      ((float4*)lsum)[k * 256 + threadIdx.x] = (float4)(0.f);
  }
}

// --------------------- merged qk + v GEMM dispatch -------------------------
// Both branches share the proven 128x128 mainloop and the SAME register
// class (VGPR ~80, 32KB LDS, 4 blk/CU) -- zero occupancy cost (R14 lesson).
// bid < 1024: qk features -> qk[m 8192][n 2048] + bias, contiguous ushort4.
// bid >= 1024: v features -> vT[b][d][n] (swapped layout scatter).
__global__ __launch_bounds__(256) void k_gemm_qkv(
    const unsigned short* __restrict__ A, const unsigned short* __restrict__ Wt,
    const float* __restrict__ bias, unsigned short* __restrict__ qk,
    unsigned short* __restrict__ vT) {
  __shared__ unsigned short As[128 * 64];
  __shared__ unsigned short Bs[128 * 64];
  const int bid = blockIdx.x;
  const int lane = threadIdx.x & 63, wave = threadIdx.x >> 6;
  if (bid < 1024) {
    // ---------------- qk branch ----------------
    f32x4 acc[4][4];
    const int tN0 = (bid & 15) * 128;
    const int tM0 = (bid >> 4) * 128;
    mma_mainloop(As, Bs, A + (size_t)tM0 * 1024, 1024,
                 Wt + (size_t)tN0 * 1024, 1024, 16, acc);
    const int ry = (wave >> 1) * 64, rx = (wave & 1) * 64;
    const int l16 = lane & 15, rq = lane >> 4;
#pragma unroll
    for (int mi = 0; mi < 4; mi++) {
      const int m = tM0 + ry + mi * 16 + l16;
#pragma unroll
      for (int nj = 0; nj < 4; nj++) {
        const int n = tN0 + rx + nj * 16 + rq * 4;
        const float4 bv = *(const float4*)&bias[n];
        ushort4 o;
        o.x = f2bf(acc[mi][nj][0] + bv.x);
        o.y = f2bf(acc[mi][nj][1] + bv.y);
        o.z = f2bf(acc[mi][nj][2] + bv.z);
        o.w = f2bf(acc[mi][nj][3] + bv.w);
        *(ushort4*)&qk[(size_t)m * 2048 + n] = o;
      }
    }
  } else {
    // ---------------- v branch ----------------
    f32x4 acc[4][4];
    const int idx = bid - 1024;
    const int tN0 = (idx & 7) * 128;   // v feature block
    const int tM0 = (idx >> 3) * 128;  // seq block
    mma_mainloop(As, Bs, A + (size_t)tM0 * 1024, 1024,
                 Wt + (size_t)(2048 + tN0) * 1024, 1024, 16, acc);
    int tM0v = tM0;
    asm volatile("" : "+v"(tM0v));  // block LICM of epilogue addresses into loop
    const int ry = (wave >> 1) * 64, rx = (wave & 1) * 64;
    const int l16 = lane & 15, rq = lane >> 4;
#pragma unroll
    for (int mi = 0; mi < 4; mi++) {
      const int m = tM0v + ry + mi * 16 + l16;  // global seq
      const int b = m >> 11, ns = m & 2047;
#pragma unroll
      for (int nj = 0; nj < 4; nj++) {
        const int d0 = tN0 + rx + nj * 16 + rq * 4;
        const float4 bv = *(const float4*)&bias[2048 + d0];
#pragma unroll
        for (int r = 0; r < 4; r++)
          vT[((size_t)(b * 1024 + d0 + r)) * 2048 + ns] =
              f2bf(acc[mi][nj][r] + ((const float*)&bv)[r]);
      }
    }
  }
}

// ------------------------- scores kernel (proven) --------------------------
// P_unnorm 128x64 tile + row-sum atomics. Triangular 1-D grid over
// (qb in 16, kb2 in 2qb+2), z = batch. 272 tiles/batch.
__global__ __launch_bounds__(256) void k_scores(const unsigned short* __restrict__ qk,
                                                unsigned short* __restrict__ P,
                                                float* __restrict__ l, float scale) {
  __shared__ unsigned short As[128 * 64];
  __shared__ unsigned short Bs[64 * 64];
  const int t = blockIdx.x, b = blockIdx.z;
  int qb = (int)((sqrtf(4.0f * (float)t + 1.0f) - 1.0f) * 0.5f);  // qb^2+qb <= t
  while (qb * (qb + 1) > t) qb--;
  while ((qb + 1) * (qb + 2) <= t) qb++;
  const int kb2 = t - qb * (qb + 1);  // 64-wide k tile, 0..2qb+1
  f32x4 acc[4][2];
  const unsigned short* Aq = qk + ((size_t)(b * 2048 + qb * 128)) * 2048;
  const unsigned short* Bk = qk + ((size_t)(b * 2048 + kb2 * 64)) * 2048 + 1024;
  mma_mainloop64(As, Bs, Aq, 2048, Bk, 2048, 16, acc);
  const int lane = threadIdx.x & 63, wave = threadIdx.x >> 6;
  const int ry = (wave >> 1) * 64, rx = (wave & 1) * 32;
  const int l16 = lane & 15, rq = lane >> 4;
  unsigned short* Pb = P + ((size_t)(b * 2048 + qb * 128)) * 2048 + (size_t)kb2 * 64;
  float* lb = l + b * 2048 + qb * 128;
#pragma unroll
  for (int mi = 0; mi < 4; mi++) {
    const int m_local = ry + mi * 16 + l16;
    const int qi = qb * 128 + m_local;
    float rowpart = 0.f;
#pragma unroll
    for (int nj = 0; nj < 2; nj++) {
      const int n_base = rx + nj * 16 + rq * 4;
      ushort4 o;
      float p;
#pragma unroll
      for (int r = 0; r < 4; r++) {
        const int kj = kb2 * 64 + n_base + r;
        p = (kj <= qi) ? __expf(acc[mi][nj][r] * scale) : 0.f;
        rowpart += p;
        ((unsigned short*)&o)[r] = f2bf(p);
      }
      *(ushort4*)&Pb[(size_t)m_local * 2048 + n_base] = o;
    }
    rowpart += __shfl_xor(rowpart, 16, 64);
    rowpart += __shfl_xor(rowpart, 32, 64);
    if (rq == 0) atomicAdd(&lb[m_local], rowpart);
  }
}

// ------------------------------- pv kernel ---------------------------------
// out[m][d] = (P[m][:] @ vT[d][:]) / l[m].  128x64 tiles, 1-D grid 1024,
// LONGEST-FIRST: t -> qb = 15 - (t>>6) (deep 32-step blocks dispatch first),
// db2 = (t&63)>>2, b = t&3.  Causal k-range (qb+1)*2 chunks.
__global__ __launch_bounds__(256) void k_pv(const unsigned short* __restrict__ P,
                                            const unsigned short* __restrict__ vT,
                                            const float* __restrict__ l,
                                            float* __restrict__ out) {
  __shared__ unsigned short As[128 * 64];
  __shared__ unsigned short Bs[64 * 64];
  const int t = blockIdx.x;
  const int qb = 15 - (t >> 6);
  const int r = t & 63;
  const int db2 = r >> 2;
  const int b = r & 3;
  f32x4 acc[4][2];
  const unsigned short* Ap = P + ((size_t)(b * 2048 + qb * 128)) * 2048;
  const unsigned short* Bv = vT + ((size_t)(b * 1024 + db2 * 64)) * 2048;
  mma_mainloop64(As, Bs, Ap, 2048, Bv, 2048, (qb + 1) * 2, acc);
  const int lane = threadIdx.x & 63, wave = threadIdx.x >> 6;
  const int ry = (wave >> 1) * 64, rx = (wave & 1) * 32;
  const int l16 = lane & 15, rq = lane >> 4;
  const float* lb = l + b * 2048 + qb * 128;
  float* ob = out + ((size_t)(b * 2048 + qb * 128)) * 1024 + db2 * 64;
#pragma unroll
  for (int mi = 0; mi < 4; mi++) {
    const int m_local = ry + mi * 16 + l16;
    const float inv = 1.0f / lb[m_local];
#pragma unroll
    for (int nj = 0; nj < 2; nj++) {
      const int n_base = rx + nj * 16 + rq * 4;
      float4 o;
      o.x = acc[mi][nj][0] * inv;
      o.y = acc[mi][nj][1] * inv;
      o.z = acc[mi][nj][2] * inv;
      o.w = acc[mi][nj][3] * inv;
      *(float4*)&ob[(size_t)m_local * 1024 + n_base] = o;
    }
  }
}

// ---------------------------------------------------------------------------

extern "C" void kernel_launch(void* const* d_in, const int* in_sizes, int n_in,
                              void* d_out, int out_size, void* d_ws, size_t ws_size,
                              hipStream_t stream) {
  const float* ctx  = (const float*)d_in[0];  // [4,2048,1024]
  const float* W    = (const float*)d_in[1];  // [1024,3072]
  const float* bias = (const float*)d_in[2];  // [3072]
  float* out = (float*)d_out;

  char* ws = (char*)d_ws;
  unsigned short* Actx = (unsigned short*)(ws + 0);          // 16,777,216
  unsigned short* Wt   = (unsigned short*)(ws + 16777216);   //  6,291,456
  unsigned short* qk   = (unsigned short*)(ws + 23068672);   // 33,554,432
  unsigned short* vT   = (unsigned short*)(ws + 56623104);   // 16,777,216
  unsigned short* P    = (unsigned short*)(ws + 73400320);   // 33,554,432
  float*          lsum = (float*)(ws + 106954752);           //     32,768

  k_prep<<<2817, 256, 0, stream>>>(ctx, Actx, W, Wt, lsum);
  k_gemm_qkv<<<1536, 256, 0, stream>>>(Actx, Wt, bias, qk, vT);
  k_scores<<<dim3(272, 1, 4), 256, 0, stream>>>(qk, P, lsum, 0.022097086912079608f);
  k_pv<<<1024, 256, 0, stream>>>(P, vT, lsum, out);
}

// Round 8
// 236.274 us; speedup vs baseline: 1.1458x; 1.0085x over previous
//
#include <hip/hip_runtime.h>
#include <cstdint>
#include <cstddef>

// ---------------------------------------------------------------------------
// Attention_84155589198714: qkv = ctx @ W + b; causal softmax(q k^T / sqrt(N)); @ v
// B=4, N=2048, D=1024. All GEMMs in bf16 MFMA (16x16x32), fp32 accumulate.
//
// R2: XOR bank swizzle (conflicts -> 0); gld16 mainloop = 700 TF at 6 blk/CU.
// R4: fused epilogues SHARING one mainloop -> LICM VGPR blowup.  (Disjoint
//   branch merge is fine ONLY within one register class -- see R14.)
// R8: 128x64 scores/pv tiles -> 241-254 us best known.
// R9-R12: 256-wide tiles + counted-vmcnt schedules: neutral/worse. ABANDONED.
// R13: instrumentation: scores=40.8us (~450 TF); ~65us inter-dispatch
//   residue (incl. harness 256MB poison fill ~41us @6.5TB/s).
// R14/R15: dispatch-merge experiments: boundary savings ~= occupancy losses
//   in both pairings (238.7 / 238.3).  Merges are a dead end; kernel-time
//   wins only from here.
// R16 (this): R7 counters showed k_gemm_qkv FETCH=136MB vs ~23MB unique:
//   N-fastest block order round-robins the 16 blocks sharing one 256KB
//   A-panel across 8 XCD L2s -> 64 panels x 256KB x 8 = 128MB ~= measured.
//   FIX: XCD-chunked bijective swizzle bid=(bid0&7)*192+(bid0>>3) (T1).
//   Per-XCD resident set: 8 A-panels (2MB) reused 16x from own L2; staging
//   waits become L2-hit (~200cy) instead of HBM (~900cy) latency.
// ---------------------------------------------------------------------------

typedef __attribute__((ext_vector_type(8))) __bf16 bf16x8;
typedef __attribute__((ext_vector_type(4))) float f32x4;

__device__ inline unsigned short f2bf(float f) {
  unsigned u = __float_as_uint(f);
  u = (u + 0x7FFFu + ((u >> 16) & 1u)) >> 16;  // RNE
  return (unsigned short)u;
}

__device__ inline void gld16(const void* g, void* l) {
  __builtin_amdgcn_global_load_lds(
      (const __attribute__((address_space(1))) unsigned int*)g,
      (__attribute__((address_space(3))) unsigned int*)l, 16, 0, 0);
}

// --------------------- 128x128 tile machinery (gemms) ----------------------
// LDS layout per tile: row r = 64 elems at r*64; 8-elem chunk c of row r at
// chunk position c ^ (r&7) (XOR bank swizzle). Swapped-operand MFMA:
// output lane&15 = m (A row), 4 acc regs = 4 consecutive n (B row).
__device__ inline void compute_tiles(const unsigned short* As, const unsigned short* Bs,
                                     int lane, int ry, int rx, f32x4 acc[4][4]) {
#pragma unroll
  for (int kk = 0; kk < 64; kk += 32) {
    const int cbase = (kk >> 3) + (lane >> 4);
    const int csw = ((cbase ^ (lane & 7)) << 3);
    bf16x8 a[4], b[4];
#pragma unroll
    for (int mi = 0; mi < 4; mi++)
      a[mi] = *(const bf16x8*)&As[(ry + mi * 16 + (lane & 15)) * 64 + csw];
#pragma unroll
    for (int nj = 0; nj < 4; nj++)
      b[nj] = *(const bf16x8*)&Bs[(rx + nj * 16 + (lane & 15)) * 64 + csw];
#pragma unroll
    for (int mi = 0; mi < 4; mi++)
#pragma unroll
      for (int nj = 0; nj < 4; nj++)
        acc[mi][nj] = __builtin_amdgcn_mfma_f32_16x16x32_bf16(b[nj], a[mi], acc[mi][nj], 0, 0, 0);
  }
}

__device__ inline void mma_mainloop(unsigned short* As, unsigned short* Bs,
                                    const unsigned short* Abase, long strideA,
                                    const unsigned short* Bbase, long strideB,
                                    int kIters, f32x4 acc[4][4]) {
  const int lane = threadIdx.x & 63, wave = threadIdx.x >> 6;
  const int ry = (wave >> 1) * 64, rx = (wave & 1) * 64;
  const int lrow = lane >> 3;
  const int lcol = ((lane & 7) ^ lrow) * 8;
#pragma unroll
  for (int mi = 0; mi < 4; mi++)
#pragma unroll
    for (int nj = 0; nj < 4; nj++) acc[mi][nj] = (f32x4)(0.f);
  for (int kt = 0; kt < kIters; kt++) {
    const int k0 = kt * 64;
    __syncthreads();
#pragma unroll
    for (int c = 0; c < 4; c++) {
      const int q = wave * 4 + c;
      const int row = q * 8 + lrow;
      gld16(Abase + (size_t)row * strideA + k0 + lcol, &As[q * 512]);
      gld16(Bbase + (size_t)row * strideB + k0 + lcol, &Bs[q * 512]);
    }
    __syncthreads();
    compute_tiles(As, Bs, lane, ry, rx, acc);
  }
}

// --------------------- 128x64 tile machinery (scores/pv) -------------------
// M=128 (A rows), N=64 (B rows). 4 waves in 2x2; wave-tile 64x32.
// acc[4][2]: mi over 4x16 rows, nj over 2x16 cols.
__device__ inline void compute_tiles64(const unsigned short* As, const unsigned short* Bs,
                                       int lane, int ry, int rx, f32x4 acc[4][2]) {
#pragma unroll
  for (int kk = 0; kk < 64; kk += 32) {
    const int cbase = (kk >> 3) + (lane >> 4);
    const int csw = ((cbase ^ (lane & 7)) << 3);
    bf16x8 a[4], b[2];
#pragma unroll
    for (int mi = 0; mi < 4; mi++)
      a[mi] = *(const bf16x8*)&As[(ry + mi * 16 + (lane & 15)) * 64 + csw];
#pragma unroll
    for (int nj = 0; nj < 2; nj++)
      b[nj] = *(const bf16x8*)&Bs[(rx + nj * 16 + (lane & 15)) * 64 + csw];
#pragma unroll
    for (int mi = 0; mi < 4; mi++)
#pragma unroll
      for (int nj = 0; nj < 2; nj++)
        acc[mi][nj] = __builtin_amdgcn_mfma_f32_16x16x32_bf16(b[nj], a[mi], acc[mi][nj], 0, 0, 0);
  }
}

__device__ inline void mma_mainloop64(unsigned short* As, unsigned short* Bs,
                                      const unsigned short* Abase, long strideA,
                                      const unsigned short* Bbase, long strideB,
                                      int kIters, f32x4 acc[4][2]) {
  const int lane = threadIdx.x & 63, wave = threadIdx.x >> 6;
  const int ry = (wave >> 1) * 64, rx = (wave & 1) * 32;
  const int lrow = lane >> 3;
  const int lcol = ((lane & 7) ^ lrow) * 8;
#pragma unroll
  for (int mi = 0; mi < 4; mi++)
#pragma unroll
    for (int nj = 0; nj < 2; nj++) acc[mi][nj] = (f32x4)(0.f);
  for (int kt = 0; kt < kIters; kt++) {
    const int k0 = kt * 64;
    __syncthreads();
#pragma unroll
    for (int c = 0; c < 4; c++) {  // A: 16 chunks of 8 rows -> 4 per wave
      const int q = wave * 4 + c;
      const int row = q * 8 + lrow;
      gld16(Abase + (size_t)row * strideA + k0 + lcol, &As[q * 512]);
    }
#pragma unroll
    for (int c = 0; c < 2; c++) {  // B: 8 chunks -> 2 per wave
      const int q = wave * 2 + c;
      const int row = q * 8 + lrow;
      gld16(Bbase + (size_t)row * strideB + k0 + lcol, &Bs[q * 512]);
    }
    __syncthreads();
    compute_tiles64(As, Bs, lane, ry, rx, acc);
  }
}

// ------------------------ prep kernel (merged) -----------------------------
// bid < 2048: bf16 convert of ctx, 4 float4/thread (2048*1024 float4 total).
// 2048 <= bid < 2816: W [1024][3072] -> Wt [3072][1024] bf16 (768 64x64 tiles).
// bid == 2816: zero lsum (8192 floats).
__global__ void k_prep(const float* __restrict__ x, unsigned short* __restrict__ y,
                       const float* __restrict__ W, unsigned short* __restrict__ Wt,
                       float* __restrict__ lsum) {
  __shared__ unsigned short sm[64 * 65];
  const int bid = blockIdx.x;
  if (bid < 2048) {
#pragma unroll
    for (int k = 0; k < 4; k++) {
      const int i = bid * 1024 + k * 256 + threadIdx.x;
      float4 v = ((const float4*)x)[i];
      ushort4 o;
      o.x = f2bf(v.x); o.y = f2bf(v.y); o.z = f2bf(v.z); o.w = f2bf(v.w);
      ((ushort4*)y)[i] = o;
    }
  } else if (bid < 2816) {
    const int t = bid - 2048;
    const int n0 = (t % 48) * 64;
    const int k0 = (t / 48) * 64;
    for (int i = threadIdx.x; i < 4096; i += 256) {
      int r = i >> 6, c = i & 63;
      sm[c * 65 + r] = f2bf(W[(size_t)(k0 + r) * 3072 + n0 + c]);
    }
    __syncthreads();
    for (int i = threadIdx.x; i < 4096; i += 256) {
      int r = i >> 6, c = i & 63;
      Wt[(size_t)(n0 + r) * 1024 + k0 + c] = sm[r * 65 + c];
    }
  } else {
#pragma unroll
    for (int k = 0; k < 8; k++)
      ((float4*)lsum)[k * 256 + threadIdx.x] = (float4)(0.f);
  }
}

// --------------------- merged qk + v GEMM dispatch -------------------------
// Both branches share the proven 128x128 mainloop and the SAME register
// class (VGPR ~112, 32KB LDS, 4 blk/CU).  R16: XCD-chunked bijective swizzle
// (1536 % 8 == 0): each XCD gets a contiguous 192-tile chunk so the 16
// N-blocks sharing one 256KB A-panel stay in ONE XCD's L2 (FETCH 136MB ->
// ~unique; staging waits become L2-hit latency).
// swz < 1024: qk features -> qk[m 8192][n 2048] + bias, contiguous ushort4.
// swz >= 1024: v features -> vT[b][d][n] (swapped layout scatter).
__global__ __launch_bounds__(256) void k_gemm_qkv(
    const unsigned short* __restrict__ A, const unsigned short* __restrict__ Wt,
    const float* __restrict__ bias, unsigned short* __restrict__ qk,
    unsigned short* __restrict__ vT) {
  __shared__ unsigned short As[128 * 64];
  __shared__ unsigned short Bs[128 * 64];
  const int bid0 = blockIdx.x;
  const int bid = (bid0 & 7) * 192 + (bid0 >> 3);  // XCD chunk swizzle (T1)
  const int lane = threadIdx.x & 63, wave = threadIdx.x >> 6;
  if (bid < 1024) {
    // ---------------- qk branch ----------------
    f32x4 acc[4][4];
    const int tN0 = (bid & 15) * 128;
    const int tM0 = (bid >> 4) * 128;
    mma_mainloop(As, Bs, A + (size_t)tM0 * 1024, 1024,
                 Wt + (size_t)tN0 * 1024, 1024, 16, acc);
    const int ry = (wave >> 1) * 64, rx = (wave & 1) * 64;
    const int l16 = lane & 15, rq = lane >> 4;
#pragma unroll
    for (int mi = 0; mi < 4; mi++) {
      const int m = tM0 + ry + mi * 16 + l16;
#pragma unroll
      for (int nj = 0; nj < 4; nj++) {
        const int n = tN0 + rx + nj * 16 + rq * 4;
        const float4 bv = *(const float4*)&bias[n];
        ushort4 o;
        o.x = f2bf(acc[mi][nj][0] + bv.x);
        o.y = f2bf(acc[mi][nj][1] + bv.y);
        o.z = f2bf(acc[mi][nj][2] + bv.z);
        o.w = f2bf(acc[mi][nj][3] + bv.w);
        *(ushort4*)&qk[(size_t)m * 2048 + n] = o;
      }
    }
  } else {
    // ---------------- v branch ----------------
    f32x4 acc[4][4];
    const int idx = bid - 1024;
    const int tN0 = (idx & 7) * 128;   // v feature block
    const int tM0 = (idx >> 3) * 128;  // seq block
    mma_mainloop(As, Bs, A + (size_t)tM0 * 1024, 1024,
                 Wt + (size_t)(2048 + tN0) * 1024, 1024, 16, acc);
    int tM0v = tM0;
    asm volatile("" : "+v"(tM0v));  // block LICM of epilogue addresses into loop
    const int ry = (wave >> 1) * 64, rx = (wave & 1) * 64;
    const int l16 = lane & 15, rq = lane >> 4;
#pragma unroll
    for (int mi = 0; mi < 4; mi++) {
      const int m = tM0v + ry + mi * 16 + l16;  // global seq
      const int b = m >> 11, ns = m & 2047;
#pragma unroll
      for (int nj = 0; nj < 4; nj++) {
        const int d0 = tN0 + rx + nj * 16 + rq * 4;
        const float4 bv = *(const float4*)&bias[2048 + d0];
#pragma unroll
        for (int r = 0; r < 4; r++)
          vT[((size_t)(b * 1024 + d0 + r)) * 2048 + ns] =
              f2bf(acc[mi][nj][r] + ((const float*)&bv)[r]);
      }
    }
  }
}

// ------------------------- scores kernel (proven) --------------------------
// P_unnorm 128x64 tile + row-sum atomics. Triangular 1-D grid over
// (qb in 16, kb2 in 2qb+2), z = batch. 272 tiles/batch.
__global__ __launch_bounds__(256) void k_scores(const unsigned short* __restrict__ qk,
                                                unsigned short* __restrict__ P,
                                                float* __restrict__ l, float scale) {
  __shared__ unsigned short As[128 * 64];
  __shared__ unsigned short Bs[64 * 64];
  const int t = blockIdx.x, b = blockIdx.z;
  int qb = (int)((sqrtf(4.0f * (float)t + 1.0f) - 1.0f) * 0.5f);  // qb^2+qb <= t
  while (qb * (qb + 1) > t) qb--;
  while ((qb + 1) * (qb + 2) <= t) qb++;
  const int kb2 = t - qb * (qb + 1);  // 64-wide k tile, 0..2qb+1
  f32x4 acc[4][2];
  const unsigned short* Aq = qk + ((size_t)(b * 2048 + qb * 128)) * 2048;
  const unsigned short* Bk = qk + ((size_t)(b * 2048 + kb2 * 64)) * 2048 + 1024;
  mma_mainloop64(As, Bs, Aq, 2048, Bk, 2048, 16, acc);
  const int lane = threadIdx.x & 63, wave = threadIdx.x >> 6;
  const int ry = (wave >> 1) * 64, rx = (wave & 1) * 32;
  const int l16 = lane & 15, rq = lane >> 4;
  unsigned short* Pb = P + ((size_t)(b * 2048 + qb * 128)) * 2048 + (size_t)kb2 * 64;
  float* lb = l + b * 2048 + qb * 128;
#pragma unroll
  for (int mi = 0; mi < 4; mi++) {
    const int m_local = ry + mi * 16 + l16;
    const int qi = qb * 128 + m_local;
    float rowpart = 0.f;
#pragma unroll
    for (int nj = 0; nj < 2; nj++) {
      const int n_base = rx + nj * 16 + rq * 4;
      ushort4 o;
      float p;
#pragma unroll
      for (int r = 0; r < 4; r++) {
        const int kj = kb2 * 64 + n_base + r;
        p = (kj <= qi) ? __expf(acc[mi][nj][r] * scale) : 0.f;
        rowpart += p;
        ((unsigned short*)&o)[r] = f2bf(p);
      }
      *(ushort4*)&Pb[(size_t)m_local * 2048 + n_base] = o;
    }
    rowpart += __shfl_xor(rowpart, 16, 64);
    rowpart += __shfl_xor(rowpart, 32, 64);
    if (rq == 0) atomicAdd(&lb[m_local], rowpart);
  }
}

// ------------------------------- pv kernel ---------------------------------
// out[m][d] = (P[m][:] @ vT[d][:]) / l[m].  128x64 tiles, 1-D grid 1024,
// LONGEST-FIRST: t -> qb = 15 - (t>>6) (deep 32-step blocks dispatch first),
// db2 = (t&63)>>2, b = t&3.  Causal k-range (qb+1)*2 chunks.
__global__ __launch_bounds__(256) void k_pv(const unsigned short* __restrict__ P,
                                            const unsigned short* __restrict__ vT,
                                            const float* __restrict__ l,
                                            float* __restrict__ out) {
  __shared__ unsigned short As[128 * 64];
  __shared__ unsigned short Bs[64 * 64];
  const int t = blockIdx.x;
  const int qb = 15 - (t >> 6);
  const int r = t & 63;
  const int db2 = r >> 2;
  const int b = r & 3;
  f32x4 acc[4][2];
  const unsigned short* Ap = P + ((size_t)(b * 2048 + qb * 128)) * 2048;
  const unsigned short* Bv = vT + ((size_t)(b * 1024 + db2 * 64)) * 2048;
  mma_mainloop64(As, Bs, Ap, 2048, Bv, 2048, (qb + 1) * 2, acc);
  const int lane = threadIdx.x & 63, wave = threadIdx.x >> 6;
  const int ry = (wave >> 1) * 64, rx = (wave & 1) * 32;
  const int l16 = lane & 15, rq = lane >> 4;
  const float* lb = l + b * 2048 + qb * 128;
  float* ob = out + ((size_t)(b * 2048 + qb * 128)) * 1024 + db2 * 64;
#pragma unroll
  for (int mi = 0; mi < 4; mi++) {
    const int m_local = ry + mi * 16 + l16;
    const float inv = 1.0f / lb[m_local];
#pragma unroll
    for (int nj = 0; nj < 2; nj++) {
      const int n_base = rx + nj * 16 + rq * 4;
      float4 o;
      o.x = acc[mi][nj][0] * inv;
      o.y = acc[mi][nj][1] * inv;
      o.z = acc[mi][nj][2] * inv;
      o.w = acc[mi][nj][3] * inv;
      *(float4*)&ob[(size_t)m_local * 1024 + n_base] = o;
    }
  }
}

// ---------------------------------------------------------------------------

extern "C" void kernel_launch(void* const* d_in, const int* in_sizes, int n_in,
                              void* d_out, int out_size, void* d_ws, size_t ws_size,
                              hipStream_t stream) {
  const float* ctx  = (const float*)d_in[0];  // [4,2048,1024]
  const float* W    = (const float*)d_in[1];  // [1024,3072]
  const float* bias = (const float*)d_in[2];  // [3072]
  float* out = (float*)d_out;

  char* ws = (char*)d_ws;
  unsigned short* Actx = (unsigned short*)(ws + 0);          // 16,777,216
  unsigned short* Wt   = (unsigned short*)(ws + 16777216);   //  6,291,456
  unsigned short* qk   = (unsigned short*)(ws + 23068672);   // 33,554,432
  unsigned short* vT   = (unsigned short*)(ws + 56623104);   // 16,777,216
  unsigned short* P    = (unsigned short*)(ws + 73400320);   // 33,554,432
  float*          lsum = (float*)(ws + 106954752);           //     32,768

  k_prep<<<2817, 256, 0, stream>>>(ctx, Actx, W, Wt, lsum);
  k_gemm_qkv<<<1536, 256, 0, stream>>>(Actx, Wt, bias, qk, vT);
  k_scores<<<dim3(272, 1, 4), 256, 0, stream>>>(qk, P, lsum, 0.022097086912079608f);
  k_pv<<<1024, 256, 0, stream>>>(P, vT, lsum, out);
}